// Round 5
// baseline (374.127 us; speedup 1.0000x reference)
//
#include <hip/hip_runtime.h>
#include <hip/hip_bf16.h>
#include <math.h>

#define B_IMG   2
#define N_PROP  2000
#define N_GT    16
#define NPROPS  2016        // N_PROP + N_GT
#define C_FEAT  256
#define H_FEAT  128
#define W_FEAT  128
#define HWF     (H_FEAT*W_FEAT)
#define POOL    7
#define BPI     512
#define NPOSMAX 128
#define NSEL    (B_IMG*BPI)     // 1024
#define K1      (C_FEAT*POOL*POOL)  // 12544
#define HID     1024
#define NHEAD   14              // 2 logits + 12 reg
#define SPLITK1 14              // KC = 896 = 28*32
#define SPLITK2 8               // KC = 128 = 4*32

typedef short bf16x8f __attribute__((ext_vector_type(8)));   // 8 bf16 = 4 VGPRs
typedef float f32x4f  __attribute__((ext_vector_type(4)));
typedef short short4v __attribute__((ext_vector_type(4)));

// ---------------------------------------------------------------- threefry
__device__ __forceinline__ void threefry2x32(unsigned k0, unsigned k1,
                                             unsigned& x0, unsigned& x1) {
  unsigned ks[3] = {k0, k1, k0 ^ k1 ^ 0x1BD11BDAu};
  const int R0[4] = {13, 15, 26, 6};
  const int R1[4] = {17, 29, 16, 24};
  x0 += ks[0]; x1 += ks[1];
#pragma unroll
  for (int g = 0; g < 5; g++) {
    const int* rot = (g & 1) ? R1 : R0;
#pragma unroll
    for (int r = 0; r < 4; r++) {
      x0 += x1;
      x1 = (x1 << rot[r]) | (x1 >> (32 - rot[r]));
      x1 ^= x0;
    }
    x0 += ks[(g + 1) % 3];
    x1 += ks[(g + 2) % 3] + (unsigned)(g + 1);
  }
}

// ---------------------------------------- sampling: rand + match + priorities
// one block per image; everything in LDS; writes prio/plab/matches.
__global__ __launch_bounds__(256) void k_sample(const float* __restrict__ proposals,
                                                const float* __restrict__ gt_boxes,
                                                const int* __restrict__ gt_labels,
                                                float* __restrict__ prio,
                                                int* __restrict__ plab,
                                                int* __restrict__ matches) {
  __shared__ float rs[NPROPS];
  __shared__ short pos_i[NPROPS];
  __shared__ float pos_r[NPROPS];
  __shared__ float gtb[N_GT * 4];
  __shared__ int   gtl[N_GT];
  __shared__ int   cnt;
  int b = blockIdx.x;
  int tid = threadIdx.x;
  int base = b * NPROPS;
  if (tid == 0) cnt = 0;
  if (tid < N_GT * 4) gtb[tid] = gt_boxes[b * N_GT * 4 + tid];
  if (tid < N_GT) gtl[tid] = gt_labels[b * N_GT + tid];
  __syncthreads();
  for (int i = tid; i < NPROPS; i += 256) {
    // threefry: element (0, base+i), bits = out0^out1
    unsigned x0 = 0u, x1 = (unsigned)(base + i);
    threefry2x32(0u, 42u, x0, x1);
    unsigned bits = x0 ^ x1;
    float r = __uint_as_float((bits >> 9) | 0x3F800000u) - 1.0f;
    rs[i] = r;
    // box
    float p0, p1, p2, p3;
    if (i < N_PROP) {
      const float4 v = *(const float4*)(proposals + ((size_t)b * N_PROP + i) * 4);
      p0 = v.x; p1 = v.y; p2 = v.z; p3 = v.w;
    } else {
      const float* g = &gtb[(i - N_PROP) * 4];
      p0 = g[0]; p1 = g[1]; p2 = g[2]; p3 = g[3];
    }
    float a2 = (p2 - p0) * (p3 - p1);
    float best = -1.0f; int bg = 0;
#pragma unroll
    for (int g = 0; g < N_GT; g++) {
      float g0 = gtb[g * 4], g1 = gtb[g * 4 + 1], g2 = gtb[g * 4 + 2], g3 = gtb[g * 4 + 3];
      float a1 = (g2 - g0) * (g3 - g1);
      float wx = fmaxf(fminf(g2, p2) - fmaxf(g0, p0), 0.0f);
      float wy = fmaxf(fminf(g3, p3) - fmaxf(g1, p1), 0.0f);
      float inter = wx * wy;
      float iou = inter / (a1 + a2 - inter);
      if (iou > best) { best = iou; bg = g; }
    }
    matches[base + i] = bg;
    int lab = (best < 0.5f) ? 0 : gtl[bg];
    plab[base + i] = lab;
    if (lab > 0) {
      int s = atomicAdd(&cnt, 1);
      pos_i[s] = (short)i; pos_r[s] = r;
    }
  }
  __syncthreads();
  int P = cnt;
  for (int s = tid; s < P; s += 256) {
    int i = pos_i[s]; float ri = pos_r[s];
    int ch = 0;
    for (int j = 0; j < P; j++) {
      float rj = pos_r[j]; int ij = pos_i[j];
      ch += (rj > ri || (rj == ri && ij < i)) ? 1 : 0;
    }
    rs[i] = (ch < NPOSMAX) ? (ri + 2.0f) : -1000000000.0f;  // pos prio
  }
  __syncthreads();
  for (int i = tid; i < NPROPS; i += 256) prio[base + i] = rs[i];
}

// ------------------------------------------------- select + gather + encode
__global__ __launch_bounds__(256) void k_select(const float* __restrict__ prio,
    const float* __restrict__ proposals, const float* __restrict__ gt_boxes,
    const int* __restrict__ matches, const int* __restrict__ plab,
    const float* __restrict__ gt_ell,
    float* __restrict__ sel_boxes, int* __restrict__ sel_labels,
    float* __restrict__ targets) {
  __shared__ float ps[B_IMG * NPROPS];
  int tid = threadIdx.x;
  for (int t = tid; t < B_IMG * NPROPS; t += 256) ps[t] = prio[t];
  __syncthreads();
  int idx = blockIdx.x * 256 + tid;
  if (idx >= B_IMG * NPROPS) return;
  int b = idx / NPROPS, i = idx - b * NPROPS;
  int base = b * NPROPS;
  float pi = ps[idx];
  int rank = 0;
#pragma unroll 8
  for (int j = 0; j < NPROPS; j++) {
    float pj = ps[base + j];
    rank += (pj > pi || (pj == pi && j < i)) ? 1 : 0;
  }
  if (rank >= BPI) return;
  int slot = b * BPI + rank;
  float p0, p1, p2, p3;
  if (i < N_PROP) {
    const float* p = proposals + ((size_t)b * N_PROP + i) * 4;
    p0 = p[0]; p1 = p[1]; p2 = p[2]; p3 = p[3];
  } else {
    const float* p = gt_boxes + ((size_t)b * N_GT + (i - N_PROP)) * 4;
    p0 = p[0]; p1 = p[1]; p2 = p[2]; p3 = p[3];
  }
  sel_boxes[slot * 4 + 0] = p0;
  sel_boxes[slot * 4 + 1] = p1;
  sel_boxes[slot * 4 + 2] = p2;
  sel_boxes[slot * 4 + 3] = p3;
  int lb = plab[idx];
  sel_labels[slot] = lb;
  int m = matches[idx];
  const float* e = gt_ell + ((size_t)b * N_GT + m) * 5;
  float ea = e[0], eb = e[1], ex = e[2], ey = e[3], eth = e[4];
  float w = fmaxf(p2 - p0, 1.0f), h = fmaxf(p3 - p1, 1.0f);
  float cx = 0.5f * (p0 + p2), cy = 0.5f * (p1 + p3);
  float* t = targets + (size_t)slot * 6;
  t[0] = (ex - cx) / w;
  t[1] = (ey - cy) / h;
  t[2] = logf(fmaxf(2.0f * ea, 0.001f) / w);
  t[3] = logf(fmaxf(2.0f * eb, 0.001f) / h);
  t[4] = sinf(2.0f * eth);
  t[5] = cosf(2.0f * eth);
}

// ------------------------------------------------------------- NCHW -> NHWC
// 64x64 tiles, float4 on both global sides. grid (HWF/64, C/64, B)
__global__ __launch_bounds__(256) void k_transpose(const float* __restrict__ in,
                                                   float* __restrict__ out) {
  __shared__ float tile[64][65];
  int b = blockIdx.z;
  int s0 = blockIdx.x * 64;   // hw
  int c0 = blockIdx.y * 64;   // channel
  const float* src = in + (size_t)b * C_FEAT * HWF;
  float* dst = out + (size_t)b * HWF * C_FEAT;
  int t = threadIdx.x;
  int hw4 = (t & 15) * 4;
  int cr  = t >> 4;
#pragma unroll
  for (int p = 0; p < 4; p++) {
    int c = cr + p * 16;
    float4 v = *(const float4*)(src + (size_t)(c0 + c) * HWF + s0 + hw4);
    tile[hw4 + 0][c] = v.x;
    tile[hw4 + 1][c] = v.y;
    tile[hw4 + 2][c] = v.z;
    tile[hw4 + 3][c] = v.w;
  }
  __syncthreads();
  int c4 = (t & 15) * 4;
  int hr = t >> 4;
#pragma unroll
  for (int p = 0; p < 4; p++) {
    int hw = hr + p * 16;
    float4 v = make_float4(tile[hw][c4], tile[hw][c4 + 1], tile[hw][c4 + 2], tile[hw][c4 + 3]);
    *(float4*)(dst + (size_t)(s0 + hw) * C_FEAT + c0 + c4) = v;
  }
}

// ------------------- fast weight cast: fp32 [K][N] -> bf16 [N][K] (64x64 tiles)
template <int PERM>
__global__ __launch_bounds__(256) void k_castT(const float* __restrict__ W,
                                               __hip_bfloat16* __restrict__ WT,
                                               int Kout) {
  __shared__ float t[64][65];
  int p  = blockIdx.z;
  int c0 = blockIdx.x * 64;
  int n0 = blockIdx.y * 64;
  int tx = threadIdx.x & 63, ty = threadIdx.x >> 6;  // 4 row-groups
#pragma unroll
  for (int i = ty; i < 64; i += 4) {
    int krow = PERM ? ((c0 + i) * 49 + p) : (c0 + i);
    t[i][tx] = W[(size_t)krow * HID + n0 + tx];
  }
  __syncthreads();
#pragma unroll
  for (int i = ty; i < 64; i += 4) {
    int kx = PERM ? (p * 256 + c0 + tx) : (c0 + tx);
    WT[(size_t)(n0 + i) * Kout + kx] = __float2bfloat16(t[tx][i]);
  }
}

// ---------------------------------------------------------------- roi align
// block 256 = 4 px-quads x 64 lanes; lane = 4 channels (float4, 1KB/wave).
// grid (NSEL, 7=py). X[n][(py*7+px)*256 + c] (bf16)
__global__ __launch_bounds__(256) void k_roialign(const float* __restrict__ featT,
                                                  const float* __restrict__ sel_boxes,
                                                  __hip_bfloat16* __restrict__ X) {
  int n = blockIdx.x;
  int py = blockIdx.y;
  int t = threadIdx.x;
  int lane = t & 63, sub = t >> 6;
  int c = lane << 2;
  int b = n >> 9;
  const float* bx = sel_boxes + (size_t)n * 4;
  float x1 = bx[0] * 0.125f, y1 = bx[1] * 0.125f;
  float x2 = bx[2] * 0.125f, y2 = bx[3] * 0.125f;
  float bw = fmaxf(x2 - x1, 1.0f) / 7.0f;
  float bh = fmaxf(y2 - y1, 1.0f) / 7.0f;
  const float* base = featT + (size_t)b * HWF * C_FEAT;
  int y0A[2]; float lyA[2];
#pragma unroll
  for (int sy = 0; sy < 2; sy++) {
    float off = ((float)(py * 2 + sy) + 0.5f) * 0.5f;
    float ys = fminf(fmaxf(y1 + off * bh, 0.0f), 127.0f);
    int y0 = (int)fminf(fmaxf(floorf(ys), 0.0f), 126.0f);
    y0A[sy] = y0; lyA[sy] = ys - (float)y0;
  }
#pragma unroll
  for (int pass = 0; pass < 2; pass++) {
    int px = sub + (pass << 2);
    if (px >= 7) break;
    float acc[4] = {0.0f, 0.0f, 0.0f, 0.0f};
#pragma unroll
    for (int sx = 0; sx < 2; sx++) {
      float off = ((float)(px * 2 + sx) + 0.5f) * 0.5f;
      float xs = fminf(fmaxf(x1 + off * bw, 0.0f), 127.0f);
      int x0 = (int)fminf(fmaxf(floorf(xs), 0.0f), 126.0f);
      float lx = xs - (float)x0;
#pragma unroll
      for (int sy = 0; sy < 2; sy++) {
        int y0 = y0A[sy]; float ly = lyA[sy];
        const float* p = base + ((size_t)(y0 * W_FEAT + x0)) * C_FEAT + c;
        float4 v00 = *(const float4*)p;
        float4 v01 = *(const float4*)(p + C_FEAT);
        float4 v10 = *(const float4*)(p + W_FEAT * C_FEAT);
        float4 v11 = *(const float4*)(p + W_FEAT * C_FEAT + C_FEAT);
        float w00 = (1.0f - ly) * (1.0f - lx), w01 = (1.0f - ly) * lx;
        float w10 = ly * (1.0f - lx), w11 = ly * lx;
        acc[0] += v00.x * w00 + v01.x * w01 + v10.x * w10 + v11.x * w11;
        acc[1] += v00.y * w00 + v01.y * w01 + v10.y * w10 + v11.y * w11;
        acc[2] += v00.z * w00 + v01.z * w01 + v10.z * w10 + v11.z * w11;
        acc[3] += v00.w * w00 + v01.w * w01 + v10.w * w10 + v11.w * w11;
      }
    }
    __hip_bfloat16 o[4] = {__float2bfloat16(acc[0] * 0.25f), __float2bfloat16(acc[1] * 0.25f),
                           __float2bfloat16(acc[2] * 0.25f), __float2bfloat16(acc[3] * 0.25f)};
    *(short4v*)&X[(size_t)n * K1 + (size_t)(py * 7 + px) * C_FEAT + c] = *(short4v*)o;
  }
}

// ------------------------------------------------------- bf16 MFMA GEMM (split-K)
// A: M x K bf16 row-major. BT: N x K bf16 row-major. P[z]: 1024x1024 fp32 partials.
// 128x128 tile, BK=32. XOR-swizzled LDS chunk layout: row r's global 16B-chunk g
// lives at slot g^(r&3) -> fragment ds_read conflicts drop 8-way -> 4-way.
__device__ __forceinline__ void gld_lds16(const __hip_bfloat16* g, __hip_bfloat16* l) {
  __builtin_amdgcn_global_load_lds(
      (const __attribute__((address_space(1))) void*)g,
      (__attribute__((address_space(3))) void*)l, 16, 0, 0);
}

__global__ __launch_bounds__(256) void k_mfma_gemm(const __hip_bfloat16* __restrict__ A,
                                                   const __hip_bfloat16* __restrict__ BT,
                                                   float* __restrict__ P,
                                                   int K, int KC) {
  __shared__ __align__(16) __hip_bfloat16 As[128 * 32];
  __shared__ __align__(16) __hip_bfloat16 Bs[128 * 32];
  int tid = threadIdx.x;
  int n0 = blockIdx.x * 128, m0 = blockIdx.y * 128;
  int kz = blockIdx.z;
  int kbeg = kz * KC;
  int srow = tid >> 2;                       // 0..63
  int scs  = tid & 3;                        // LDS chunk slot
  int sg   = scs ^ (srow & 3);               // global chunk staged by this lane
  int scol = sg << 3;                        // element offset
  int wave = tid >> 6, lane = tid & 63;
  int wm = (wave & 1) * 64, wn = (wave >> 1) * 64;
  int lm = lane & 15, quad = lane >> 4;
  int fco = ((quad ^ (lm & 3)) << 3);        // swizzled fragment chunk offset
  f32x4f acc[4][4] = {};
  for (int k0 = kbeg; k0 < kbeg + KC; k0 += 32) {
    __syncthreads();
    gld_lds16(A  + (size_t)(m0 + srow) * K + k0 + scol,      &As[srow * 32 + scs * 8]);
    gld_lds16(A  + (size_t)(m0 + 64 + srow) * K + k0 + scol, &As[(64 + srow) * 32 + scs * 8]);
    gld_lds16(BT + (size_t)(n0 + srow) * K + k0 + scol,      &Bs[srow * 32 + scs * 8]);
    gld_lds16(BT + (size_t)(n0 + 64 + srow) * K + k0 + scol, &Bs[(64 + srow) * 32 + scs * 8]);
    __syncthreads();
    bf16x8f af[4], bf[4];
#pragma unroll
    for (int i = 0; i < 4; i++)
      af[i] = *(const bf16x8f*)&As[(wm + i * 16 + lm) * 32 + fco];
#pragma unroll
    for (int j = 0; j < 4; j++)
      bf[j] = *(const bf16x8f*)&Bs[(wn + j * 16 + lm) * 32 + fco];
#pragma unroll
    for (int i = 0; i < 4; i++)
#pragma unroll
      for (int j = 0; j < 4; j++)
        acc[i][j] = __builtin_amdgcn_mfma_f32_16x16x32_bf16(af[i], bf[j], acc[i][j], 0, 0, 0);
  }
  // C/D layout: col = lane&15, row = quad*4 + reg
#pragma unroll
  for (int i = 0; i < 4; i++)
#pragma unroll
    for (int j = 0; j < 4; j++) {
      float* base = P + ((size_t)kz << 20)
                      + (size_t)(m0 + wm + i * 16 + quad * 4) * HID
                      + (n0 + wn + j * 16 + lm);
#pragma unroll
      for (int r = 0; r < 4; r++) base[(size_t)r * HID] = acc[i][j][r];
    }
}

// reduce split-K partials + bias + relu; OUTBF16 chooses output dtype
template <int Z, int OUTBF16>
__global__ __launch_bounds__(256) void k_reduce(const float* __restrict__ P,
                                                const float* __restrict__ bias,
                                                void* __restrict__ O) {
  int idx4 = blockIdx.x * 256 + threadIdx.x;
  int m = idx4 >> 8;
  int n4 = (idx4 & 255) << 2;
  float4 s = *(const float4*)(bias + n4);
#pragma unroll
  for (int z = 0; z < Z; z++) {
    float4 p = *(const float4*)(P + ((size_t)z << 20) + ((size_t)m << 10) + n4);
    s.x += p.x; s.y += p.y; s.z += p.z; s.w += p.w;
  }
  s.x = fmaxf(s.x, 0.0f); s.y = fmaxf(s.y, 0.0f);
  s.z = fmaxf(s.z, 0.0f); s.w = fmaxf(s.w, 0.0f);
  if (OUTBF16) {
    __hip_bfloat16 t[4] = {__float2bfloat16(s.x), __float2bfloat16(s.y),
                           __float2bfloat16(s.z), __float2bfloat16(s.w)};
    *(short4v*)((__hip_bfloat16*)O + ((size_t)m << 10) + n4) = *(short4v*)t;
  } else {
    *(float4*)((float*)O + ((size_t)m << 10) + n4) = s;
  }
}

// --------------------------------------------------------------- head GEMM
__global__ __launch_bounds__(256) void k_head(const float* __restrict__ H2,
                                              const float* __restrict__ wc,
                                              const float* __restrict__ bc,
                                              const float* __restrict__ wr,
                                              const float* __restrict__ br,
                                              float* __restrict__ Y) {
  __shared__ float Wl[HID * NHEAD];
  int tid = threadIdx.x;
  for (int t = tid; t < HID * NHEAD; t += 256) {
    int k = t / NHEAD, j = t - k * NHEAD;
    Wl[t] = (j < 2) ? wc[k * 2 + j] : wr[k * 12 + (j - 2)];
  }
  __syncthreads();
  int wave = tid >> 6, lane = tid & 63;
  int row = blockIdx.x * 4 + wave;
  float acc[NHEAD];
#pragma unroll
  for (int j = 0; j < NHEAD; j++) acc[j] = 0.0f;
  const float* h = H2 + (size_t)row * HID;
  for (int k = lane; k < HID; k += 64) {
    float hv = h[k];
    const float* wrow = &Wl[k * NHEAD];
#pragma unroll
    for (int j = 0; j < NHEAD; j++) acc[j] = fmaf(hv, wrow[j], acc[j]);
  }
#pragma unroll
  for (int j = 0; j < NHEAD; j++) {
    float v = acc[j];
    for (int off = 32; off > 0; off >>= 1) v += __shfl_down(v, off);
    if (lane == 0) Y[(size_t)row * NHEAD + j] = v + ((j < 2) ? bc[j] : br[j - 2]);
  }
}

// ------------------------------------------------------------------- losses
__global__ __launch_bounds__(1024) void k_loss(const float* __restrict__ Y,
                                               const int* __restrict__ sel_labels,
                                               const float* __restrict__ T,
                                               float* __restrict__ out) {
  __shared__ float sc[1024];
  __shared__ float sr[1024];
  int n = threadIdx.x;
  float l0 = Y[(size_t)n * NHEAD + 0], l1 = Y[(size_t)n * NHEAD + 1];
  int lb = sel_labels[n];
  float mx = fmaxf(l0, l1);
  float lse = mx + logf(expf(l0 - mx) + expf(l1 - mx));
  float ce = lse - (lb ? l1 : l0);
  float reg = 0.0f;
  if (lb > 0) {
    const float beta = 1.0f / 9.0f;
    const float* pr = Y + (size_t)n * NHEAD + 2 + lb * 6;
    const float* t = T + (size_t)n * 6;
#pragma unroll
    for (int j = 0; j < 6; j++) {
      float d = fabsf(pr[j] - t[j]);
      reg += (d < beta) ? (0.5f * d * d / beta) : (d - 0.5f * beta);
    }
  }
  sc[n] = ce; sr[n] = reg;
  __syncthreads();
  for (int s = 512; s > 0; s >>= 1) {
    if (n < s) { sc[n] += sc[n + s]; sr[n] += sr[n + s]; }
    __syncthreads();
  }
  if (n == 0) {
    out[0] = sc[0] * (1.0f / 1024.0f);
    out[1] = sr[0] * (1.0f / 1024.0f);
  }
}

// ------------------------------------------------------------------ launch
extern "C" void kernel_launch(void* const* d_in, const int* in_sizes, int n_in,
                              void* d_out, int out_size, void* d_ws, size_t ws_size,
                              hipStream_t stream) {
  const float* features  = (const float*)d_in[0];
  const float* proposals = (const float*)d_in[1];
  const float* gt_boxes  = (const float*)d_in[2];
  const int*   gt_labels = (const int*)d_in[3];
  const float* gt_ell    = (const float*)d_in[4];
  const float* w1 = (const float*)d_in[5];
  const float* b1 = (const float*)d_in[6];
  const float* w2 = (const float*)d_in[7];
  const float* b2 = (const float*)d_in[8];
  const float* wc = (const float*)d_in[9];
  const float* bc = (const float*)d_in[10];
  const float* wr = (const float*)d_in[11];
  const float* br = (const float*)d_in[12];
  float* out = (float*)d_out;

  char* ws = (char*)d_ws;
  size_t off = 0;
  auto take = [&](size_t bytes) -> void* {
    void* p = ws + off;
    off = (off + bytes + 255) & ~(size_t)255;
    return p;
  };
  // region0 hosts featT (33.5 MB, dead after roialign) then P (14x4 MiB partials)
  float* P     = (float*)take((size_t)SPLITK1 * HID * HID * 4);        // 58.7 MB
  float* featT = P;                                                    // alias
  __hip_bfloat16* Xb  = (__hip_bfloat16*)take((size_t)NSEL * K1 * 2);  // 25.7 MB
  // Xb dead after GEMM1: H2s + Y alias into it
  float* H2s = (float*)Xb;                                             // 4.2 MB
  float* Y   = (float*)((char*)Xb + ((size_t)NSEL * HID * 4 + 256));
  __hip_bfloat16* W1T = (__hip_bfloat16*)take((size_t)HID * K1 * 2);   // 25.7 MB
  __hip_bfloat16* W2T = (__hip_bfloat16*)take((size_t)HID * HID * 2);  // 2.1 MB
  __hip_bfloat16* H1b = (__hip_bfloat16*)take((size_t)NSEL * HID * 2); // 2.1 MB
  int*   matches   = (int*)take((size_t)B_IMG * NPROPS * 4);
  int*   plab      = (int*)take((size_t)B_IMG * NPROPS * 4);
  float* prio      = (float*)take((size_t)B_IMG * NPROPS * 4);
  float* sel_boxes = (float*)take((size_t)NSEL * 4 * 4);
  int*   sel_lab   = (int*)take((size_t)NSEL * 4);
  float* targets   = (float*)take((size_t)NSEL * 6 * 4);

  k_sample<<<B_IMG, 256, 0, stream>>>(proposals, gt_boxes, gt_labels, prio, plab, matches);
  k_transpose<<<dim3(HWF / 64, C_FEAT / 64, B_IMG), 256, 0, stream>>>(features, featT);
  k_castT<1><<<dim3(C_FEAT / 64, HID / 64, 49), 256, 0, stream>>>(w1, W1T, K1);
  k_castT<0><<<dim3(HID / 64, HID / 64, 1), 256, 0, stream>>>(w2, W2T, HID);
  k_select<<<(B_IMG * NPROPS + 255) / 256, 256, 0, stream>>>(prio, proposals, gt_boxes,
                                                             matches, plab, gt_ell,
                                                             sel_boxes, sel_lab, targets);
  k_roialign<<<dim3(NSEL, POOL), 256, 0, stream>>>(featT, sel_boxes, Xb);

  // GEMM1: Xb(1024 x 12544) @ W1T^T, split-K=14 (KC=896), reduce+relu -> H1b (bf16)
  k_mfma_gemm<<<dim3(8, 8, SPLITK1), 256, 0, stream>>>(Xb, W1T, P, K1, K1 / SPLITK1);
  k_reduce<SPLITK1, 1><<<1024, 256, 0, stream>>>(P, b1, H1b);
  // GEMM2: H1b(1024x1024) @ W2T^T, split-K=8 (KC=128), reduce+relu -> H2 (fp32)
  k_mfma_gemm<<<dim3(8, 8, SPLITK2), 256, 0, stream>>>(H1b, W2T, P, HID, HID / SPLITK2);
  k_reduce<SPLITK2, 0><<<1024, 256, 0, stream>>>(P, b2, H2s);

  k_head<<<NSEL / 4, 256, 0, stream>>>(H2s, wc, bc, wr, br, Y);
  k_loss<<<1, 1024, 0, stream>>>(Y, sel_lab, targets, out);
}

// Round 6
// 315.451 us; speedup vs baseline: 1.1860x; 1.1860x over previous
//
#include <hip/hip_runtime.h>
#include <hip/hip_bf16.h>
#include <math.h>

#define B_IMG   2
#define N_PROP  2000
#define N_GT    16
#define NPROPS  2016        // N_PROP + N_GT
#define C_FEAT  256
#define H_FEAT  128
#define W_FEAT  128
#define HWF     (H_FEAT*W_FEAT)
#define POOL    7
#define BPI     512
#define NPOSMAX 128
#define NSEL    (B_IMG*BPI)     // 1024
#define K1      (C_FEAT*POOL*POOL)  // 12544
#define HID     1024
#define NHEAD   14              // 2 logits + 12 reg
#define SPLITK1 14              // KC = 896 = 28*32
#define SPLITK2 8               // KC = 128 = 4*32

typedef short bf16x8f __attribute__((ext_vector_type(8)));   // 8 bf16 = 4 VGPRs
typedef float f32x4f  __attribute__((ext_vector_type(4)));
typedef short short4v __attribute__((ext_vector_type(4)));

// ---------------------------------------------------------------- threefry
__device__ __forceinline__ void threefry2x32(unsigned k0, unsigned k1,
                                             unsigned& x0, unsigned& x1) {
  unsigned ks[3] = {k0, k1, k0 ^ k1 ^ 0x1BD11BDAu};
  const int R0[4] = {13, 15, 26, 6};
  const int R1[4] = {17, 29, 16, 24};
  x0 += ks[0]; x1 += ks[1];
#pragma unroll
  for (int g = 0; g < 5; g++) {
    const int* rot = (g & 1) ? R1 : R0;
#pragma unroll
    for (int r = 0; r < 4; r++) {
      x0 += x1;
      x1 = (x1 << rot[r]) | (x1 >> (32 - rot[r]));
      x1 ^= x0;
    }
    x0 += ks[(g + 1) % 3];
    x1 += ks[(g + 2) % 3] + (unsigned)(g + 1);
  }
}

// ---------------------------------------- sampling: rand + match + priorities
__global__ __launch_bounds__(256) void k_sample(const float* __restrict__ proposals,
                                                const float* __restrict__ gt_boxes,
                                                const int* __restrict__ gt_labels,
                                                float* __restrict__ prio,
                                                int* __restrict__ plab,
                                                int* __restrict__ matches) {
  __shared__ float rs[NPROPS];
  __shared__ short pos_i[NPROPS];
  __shared__ float pos_r[NPROPS];
  __shared__ float gtb[N_GT * 4];
  __shared__ int   gtl[N_GT];
  __shared__ int   cnt;
  int b = blockIdx.x;
  int tid = threadIdx.x;
  int base = b * NPROPS;
  if (tid == 0) cnt = 0;
  if (tid < N_GT * 4) gtb[tid] = gt_boxes[b * N_GT * 4 + tid];
  if (tid < N_GT) gtl[tid] = gt_labels[b * N_GT + tid];
  __syncthreads();
  for (int i = tid; i < NPROPS; i += 256) {
    unsigned x0 = 0u, x1 = (unsigned)(base + i);
    threefry2x32(0u, 42u, x0, x1);
    unsigned bits = x0 ^ x1;
    float r = __uint_as_float((bits >> 9) | 0x3F800000u) - 1.0f;
    rs[i] = r;
    float p0, p1, p2, p3;
    if (i < N_PROP) {
      const float4 v = *(const float4*)(proposals + ((size_t)b * N_PROP + i) * 4);
      p0 = v.x; p1 = v.y; p2 = v.z; p3 = v.w;
    } else {
      const float* g = &gtb[(i - N_PROP) * 4];
      p0 = g[0]; p1 = g[1]; p2 = g[2]; p3 = g[3];
    }
    float a2 = (p2 - p0) * (p3 - p1);
    float best = -1.0f; int bg = 0;
#pragma unroll
    for (int g = 0; g < N_GT; g++) {
      float g0 = gtb[g * 4], g1 = gtb[g * 4 + 1], g2 = gtb[g * 4 + 2], g3 = gtb[g * 4 + 3];
      float a1 = (g2 - g0) * (g3 - g1);
      float wx = fmaxf(fminf(g2, p2) - fmaxf(g0, p0), 0.0f);
      float wy = fmaxf(fminf(g3, p3) - fmaxf(g1, p1), 0.0f);
      float inter = wx * wy;
      float iou = inter / (a1 + a2 - inter);
      if (iou > best) { best = iou; bg = g; }
    }
    matches[base + i] = bg;
    int lab = (best < 0.5f) ? 0 : gtl[bg];
    plab[base + i] = lab;
    if (lab > 0) {
      int s = atomicAdd(&cnt, 1);
      pos_i[s] = (short)i; pos_r[s] = r;
    }
  }
  __syncthreads();
  int P = cnt;
  for (int s = tid; s < P; s += 256) {
    int i = pos_i[s]; float ri = pos_r[s];
    int ch = 0;
    for (int j = 0; j < P; j++) {
      float rj = pos_r[j]; int ij = pos_i[j];
      ch += (rj > ri || (rj == ri && ij < i)) ? 1 : 0;
    }
    rs[i] = (ch < NPOSMAX) ? (ri + 2.0f) : -1000000000.0f;
  }
  __syncthreads();
  for (int i = tid; i < NPROPS; i += 256) prio[base + i] = rs[i];
}

// ------------------------------------------------- select + gather + encode
// wave-per-candidate: grid (NPROPS/4, B_IMG), 4 waves/block.
__global__ __launch_bounds__(256) void k_select(const float* __restrict__ prio,
    const float* __restrict__ proposals, const float* __restrict__ gt_boxes,
    const int* __restrict__ matches, const int* __restrict__ plab,
    const float* __restrict__ gt_ell,
    float* __restrict__ sel_boxes, int* __restrict__ sel_labels,
    float* __restrict__ targets) {
  int tid = threadIdx.x;
  int wave = tid >> 6, lane = tid & 63;
  int b = blockIdx.y;
  int base = b * NPROPS;
  int i = blockIdx.x * 4 + wave;       // 0..2015
  float pi = prio[base + i];
  int rank = 0;
  for (int j = lane; j < NPROPS; j += 64) {
    float pj = prio[base + j];
    rank += (pj > pi || (pj == pi && j < i)) ? 1 : 0;
  }
#pragma unroll
  for (int off = 32; off > 0; off >>= 1) rank += __shfl_down(rank, off);
  if (lane != 0 || rank >= BPI) return;
  int slot = b * BPI + rank;
  float p0, p1, p2, p3;
  if (i < N_PROP) {
    const float* p = proposals + ((size_t)b * N_PROP + i) * 4;
    p0 = p[0]; p1 = p[1]; p2 = p[2]; p3 = p[3];
  } else {
    const float* p = gt_boxes + ((size_t)b * N_GT + (i - N_PROP)) * 4;
    p0 = p[0]; p1 = p[1]; p2 = p[2]; p3 = p[3];
  }
  sel_boxes[slot * 4 + 0] = p0;
  sel_boxes[slot * 4 + 1] = p1;
  sel_boxes[slot * 4 + 2] = p2;
  sel_boxes[slot * 4 + 3] = p3;
  int lb = plab[base + i];
  sel_labels[slot] = lb;
  int m = matches[base + i];
  const float* e = gt_ell + ((size_t)b * N_GT + m) * 5;
  float ea = e[0], eb = e[1], ex = e[2], ey = e[3], eth = e[4];
  float w = fmaxf(p2 - p0, 1.0f), h = fmaxf(p3 - p1, 1.0f);
  float cx = 0.5f * (p0 + p2), cy = 0.5f * (p1 + p3);
  float* t = targets + (size_t)slot * 6;
  t[0] = (ex - cx) / w;
  t[1] = (ey - cy) / h;
  t[2] = logf(fmaxf(2.0f * ea, 0.001f) / w);
  t[3] = logf(fmaxf(2.0f * eb, 0.001f) / h);
  t[4] = sinf(2.0f * eth);
  t[5] = cosf(2.0f * eth);
}

// ------------------------------------------------------------- NCHW -> NHWC
__global__ __launch_bounds__(256) void k_transpose(const float* __restrict__ in,
                                                   float* __restrict__ out) {
  __shared__ float tile[64][65];
  int b = blockIdx.z;
  int s0 = blockIdx.x * 64;   // hw
  int c0 = blockIdx.y * 64;   // channel
  const float* src = in + (size_t)b * C_FEAT * HWF;
  float* dst = out + (size_t)b * HWF * C_FEAT;
  int t = threadIdx.x;
  int hw4 = (t & 15) * 4;
  int cr  = t >> 4;
#pragma unroll
  for (int p = 0; p < 4; p++) {
    int c = cr + p * 16;
    float4 v = *(const float4*)(src + (size_t)(c0 + c) * HWF + s0 + hw4);
    tile[hw4 + 0][c] = v.x;
    tile[hw4 + 1][c] = v.y;
    tile[hw4 + 2][c] = v.z;
    tile[hw4 + 3][c] = v.w;
  }
  __syncthreads();
  int c4 = (t & 15) * 4;
  int hr = t >> 4;
#pragma unroll
  for (int p = 0; p < 4; p++) {
    int hw = hr + p * 16;
    float4 v = make_float4(tile[hw][c4], tile[hw][c4 + 1], tile[hw][c4 + 2], tile[hw][c4 + 3]);
    *(float4*)(dst + (size_t)(s0 + hw) * C_FEAT + c0 + c4) = v;
  }
}

// ------------------- fast weight cast: fp32 [K][N] -> bf16 [N][K] (64x64 tiles)
template <int PERM>
__global__ __launch_bounds__(256) void k_castT(const float* __restrict__ W,
                                               __hip_bfloat16* __restrict__ WT,
                                               int Kout) {
  __shared__ float t[64][65];
  int p  = blockIdx.z;
  int c0 = blockIdx.x * 64;
  int n0 = blockIdx.y * 64;
  int tx = threadIdx.x & 63, ty = threadIdx.x >> 6;
#pragma unroll
  for (int i = ty; i < 64; i += 4) {
    int krow = PERM ? ((c0 + i) * 49 + p) : (c0 + i);
    t[i][tx] = W[(size_t)krow * HID + n0 + tx];
  }
  __syncthreads();
#pragma unroll
  for (int i = ty; i < 64; i += 4) {
    int kx = PERM ? (p * 256 + c0 + tx) : (c0 + tx);
    WT[(size_t)(n0 + i) * Kout + kx] = __float2bfloat16(t[tx][i]);
  }
}

// ---------------------------------------------------------------- roi align
__global__ __launch_bounds__(256) void k_roialign(const float* __restrict__ featT,
                                                  const float* __restrict__ sel_boxes,
                                                  __hip_bfloat16* __restrict__ X) {
  int n = blockIdx.x;
  int py = blockIdx.y;
  int t = threadIdx.x;
  int lane = t & 63, sub = t >> 6;
  int c = lane << 2;
  int b = n >> 9;
  const float* bx = sel_boxes + (size_t)n * 4;
  float x1 = bx[0] * 0.125f, y1 = bx[1] * 0.125f;
  float x2 = bx[2] * 0.125f, y2 = bx[3] * 0.125f;
  float bw = fmaxf(x2 - x1, 1.0f) / 7.0f;
  float bh = fmaxf(y2 - y1, 1.0f) / 7.0f;
  const float* base = featT + (size_t)b * HWF * C_FEAT;
  int y0A[2]; float lyA[2];
#pragma unroll
  for (int sy = 0; sy < 2; sy++) {
    float off = ((float)(py * 2 + sy) + 0.5f) * 0.5f;
    float ys = fminf(fmaxf(y1 + off * bh, 0.0f), 127.0f);
    int y0 = (int)fminf(fmaxf(floorf(ys), 0.0f), 126.0f);
    y0A[sy] = y0; lyA[sy] = ys - (float)y0;
  }
#pragma unroll
  for (int pass = 0; pass < 2; pass++) {
    int px = sub + (pass << 2);
    if (px >= 7) break;
    float acc[4] = {0.0f, 0.0f, 0.0f, 0.0f};
#pragma unroll
    for (int sx = 0; sx < 2; sx++) {
      float off = ((float)(px * 2 + sx) + 0.5f) * 0.5f;
      float xs = fminf(fmaxf(x1 + off * bw, 0.0f), 127.0f);
      int x0 = (int)fminf(fmaxf(floorf(xs), 0.0f), 126.0f);
      float lx = xs - (float)x0;
#pragma unroll
      for (int sy = 0; sy < 2; sy++) {
        int y0 = y0A[sy]; float ly = lyA[sy];
        const float* p = base + ((size_t)(y0 * W_FEAT + x0)) * C_FEAT + c;
        float4 v00 = *(const float4*)p;
        float4 v01 = *(const float4*)(p + C_FEAT);
        float4 v10 = *(const float4*)(p + W_FEAT * C_FEAT);
        float4 v11 = *(const float4*)(p + W_FEAT * C_FEAT + C_FEAT);
        float w00 = (1.0f - ly) * (1.0f - lx), w01 = (1.0f - ly) * lx;
        float w10 = ly * (1.0f - lx), w11 = ly * lx;
        acc[0] += v00.x * w00 + v01.x * w01 + v10.x * w10 + v11.x * w11;
        acc[1] += v00.y * w00 + v01.y * w01 + v10.y * w10 + v11.y * w11;
        acc[2] += v00.z * w00 + v01.z * w01 + v10.z * w10 + v11.z * w11;
        acc[3] += v00.w * w00 + v01.w * w01 + v10.w * w10 + v11.w * w11;
      }
    }
    __hip_bfloat16 o[4] = {__float2bfloat16(acc[0] * 0.25f), __float2bfloat16(acc[1] * 0.25f),
                           __float2bfloat16(acc[2] * 0.25f), __float2bfloat16(acc[3] * 0.25f)};
    *(short4v*)&X[(size_t)n * K1 + (size_t)(py * 7 + px) * C_FEAT + c] = *(short4v*)o;
  }
}

// ------------------------------------------------------- bf16 MFMA GEMM (split-K)
// AM = A-tile rows (256 or 128); B-tile = 128 cols; BK=32; blockDim = AM*2.
// XOR-swizzled LDS chunks: row r's global 16B-chunk g at slot g^(r&3).
__device__ __forceinline__ void gld_lds16(const __hip_bfloat16* g, __hip_bfloat16* l) {
  __builtin_amdgcn_global_load_lds(
      (const __attribute__((address_space(1))) void*)g,
      (__attribute__((address_space(3))) void*)l, 16, 0, 0);
}

template <int AM>
__global__ __launch_bounds__(AM * 2) void k_mfma_gemm(const __hip_bfloat16* __restrict__ A,
                                                      const __hip_bfloat16* __restrict__ BT,
                                                      float* __restrict__ P,
                                                      int K, int KC) {
  const int TPB = AM * 2;
  __shared__ __align__(16) __hip_bfloat16 As[AM * 32];
  __shared__ __align__(16) __hip_bfloat16 Bs[128 * 32];
  int tid = threadIdx.x;
  int n0 = blockIdx.x * 128, m0 = blockIdx.y * AM;
  int kz = blockIdx.z;
  int kbeg = kz * KC;
  int srow = tid >> 2;                       // 0..TPB/4-1
  int scs  = tid & 3;                        // LDS chunk slot
  int sg   = scs ^ (srow & 3);               // global chunk staged by this lane
  int scol = sg << 3;
  int wave = tid >> 6, lane = tid & 63;
  const int WMW = AM / 64;
  int wm = (wave % WMW) * 64, wn = (wave / WMW) * 64;
  int lm = lane & 15, quad = lane >> 4;
  int fco = ((quad ^ (lm & 3)) << 3);        // swizzled fragment chunk offset
  f32x4f acc[4][4] = {};
  for (int k0 = kbeg; k0 < kbeg + KC; k0 += 32) {
    __syncthreads();
#pragma unroll
    for (int r0 = 0; r0 < AM; r0 += TPB / 4)
      gld_lds16(A + (size_t)(m0 + r0 + srow) * K + k0 + scol, &As[(r0 + srow) * 32 + scs * 8]);
#pragma unroll
    for (int r0 = 0; r0 < 128; r0 += TPB / 4)
      gld_lds16(BT + (size_t)(n0 + r0 + srow) * K + k0 + scol, &Bs[(r0 + srow) * 32 + scs * 8]);
    __syncthreads();
    bf16x8f af[4], bf[4];
#pragma unroll
    for (int i = 0; i < 4; i++)
      af[i] = *(const bf16x8f*)&As[(wm + i * 16 + lm) * 32 + fco];
#pragma unroll
    for (int j = 0; j < 4; j++)
      bf[j] = *(const bf16x8f*)&Bs[(wn + j * 16 + lm) * 32 + fco];
#pragma unroll
    for (int i = 0; i < 4; i++)
#pragma unroll
      for (int j = 0; j < 4; j++)
        acc[i][j] = __builtin_amdgcn_mfma_f32_16x16x32_bf16(af[i], bf[j], acc[i][j], 0, 0, 0);
  }
  // C/D layout: col = lane&15, row = quad*4 + reg
#pragma unroll
  for (int i = 0; i < 4; i++)
#pragma unroll
    for (int j = 0; j < 4; j++) {
      float* base = P + ((size_t)kz << 20)
                      + (size_t)(m0 + wm + i * 16 + quad * 4) * HID
                      + (n0 + wn + j * 16 + lm);
#pragma unroll
      for (int r = 0; r < 4; r++) base[(size_t)r * HID] = acc[i][j][r];
    }
}

// reduce split-K partials + bias + relu -> bf16 (after GEMM1)
template <int Z>
__global__ __launch_bounds__(256) void k_reduce(const float* __restrict__ P,
                                                const float* __restrict__ bias,
                                                __hip_bfloat16* __restrict__ O) {
  int idx4 = blockIdx.x * 256 + threadIdx.x;
  int m = idx4 >> 8;
  int n4 = (idx4 & 255) << 2;
  float4 s = *(const float4*)(bias + n4);
#pragma unroll
  for (int z = 0; z < Z; z++) {
    float4 p = *(const float4*)(P + ((size_t)z << 20) + ((size_t)m << 10) + n4);
    s.x += p.x; s.y += p.y; s.z += p.z; s.w += p.w;
  }
  __hip_bfloat16 t[4] = {__float2bfloat16(fmaxf(s.x, 0.0f)), __float2bfloat16(fmaxf(s.y, 0.0f)),
                         __float2bfloat16(fmaxf(s.z, 0.0f)), __float2bfloat16(fmaxf(s.w, 0.0f))};
  *(short4v*)(O + ((size_t)m << 10) + n4) = *(short4v*)t;
}

// ---------------------- reduce GEMM2 partials + bias + relu + head, fused.
// one block per row m; thread owns h[n4..n4+3]; block-reduce 14 head dots.
__global__ __launch_bounds__(256) void k_reduce_head(const float* __restrict__ P,
                                                     const float* __restrict__ bias,
                                                     const float* __restrict__ wc,
                                                     const float* __restrict__ bc,
                                                     const float* __restrict__ wr,
                                                     const float* __restrict__ br,
                                                     float* __restrict__ Y) {
  __shared__ float part[4][NHEAD];
  int m = blockIdx.x, tid = threadIdx.x;
  int n4 = tid << 2;
  float4 s = *(const float4*)(bias + n4);
#pragma unroll
  for (int z = 0; z < SPLITK2; z++) {
    float4 p = *(const float4*)(P + ((size_t)z << 20) + ((size_t)m << 10) + n4);
    s.x += p.x; s.y += p.y; s.z += p.z; s.w += p.w;
  }
  float hv4[4] = {fmaxf(s.x, 0.0f), fmaxf(s.y, 0.0f), fmaxf(s.z, 0.0f), fmaxf(s.w, 0.0f)};
  float a[NHEAD];
#pragma unroll
  for (int j = 0; j < NHEAD; j++) a[j] = 0.0f;
#pragma unroll
  for (int q = 0; q < 4; q++) {
    int kk = n4 + q;
    float hv = hv4[q];
    float2 wcv = *(const float2*)(wc + kk * 2);
    float4 w0 = *(const float4*)(wr + kk * 12);
    float4 w1 = *(const float4*)(wr + kk * 12 + 4);
    float4 w2 = *(const float4*)(wr + kk * 12 + 8);
    a[0] += hv * wcv.x;  a[1] += hv * wcv.y;
    a[2] += hv * w0.x;   a[3] += hv * w0.y;  a[4] += hv * w0.z;  a[5] += hv * w0.w;
    a[6] += hv * w1.x;   a[7] += hv * w1.y;  a[8] += hv * w1.z;  a[9] += hv * w1.w;
    a[10] += hv * w2.x;  a[11] += hv * w2.y; a[12] += hv * w2.z; a[13] += hv * w2.w;
  }
#pragma unroll
  for (int j = 0; j < NHEAD; j++)
#pragma unroll
    for (int off = 32; off > 0; off >>= 1) a[j] += __shfl_down(a[j], off);
  int wave = tid >> 6, lane = tid & 63;
  if (lane == 0)
#pragma unroll
    for (int j = 0; j < NHEAD; j++) part[wave][j] = a[j];
  __syncthreads();
  if (tid < NHEAD) {
    float v = part[0][tid] + part[1][tid] + part[2][tid] + part[3][tid];
    Y[(size_t)m * NHEAD + tid] = v + ((tid < 2) ? bc[tid] : br[tid - 2]);
  }
}

// ------------------------------------------------------------------- losses
__global__ __launch_bounds__(1024) void k_loss(const float* __restrict__ Y,
                                               const int* __restrict__ sel_labels,
                                               const float* __restrict__ T,
                                               float* __restrict__ out) {
  __shared__ float sc[1024];
  __shared__ float sr[1024];
  int n = threadIdx.x;
  float l0 = Y[(size_t)n * NHEAD + 0], l1 = Y[(size_t)n * NHEAD + 1];
  int lb = sel_labels[n];
  float mx = fmaxf(l0, l1);
  float lse = mx + logf(expf(l0 - mx) + expf(l1 - mx));
  float ce = lse - (lb ? l1 : l0);
  float reg = 0.0f;
  if (lb > 0) {
    const float beta = 1.0f / 9.0f;
    const float* pr = Y + (size_t)n * NHEAD + 2 + lb * 6;
    const float* t = T + (size_t)n * 6;
#pragma unroll
    for (int j = 0; j < 6; j++) {
      float d = fabsf(pr[j] - t[j]);
      reg += (d < beta) ? (0.5f * d * d / beta) : (d - 0.5f * beta);
    }
  }
  sc[n] = ce; sr[n] = reg;
  __syncthreads();
  for (int s = 512; s > 0; s >>= 1) {
    if (n < s) { sc[n] += sc[n + s]; sr[n] += sr[n + s]; }
    __syncthreads();
  }
  if (n == 0) {
    out[0] = sc[0] * (1.0f / 1024.0f);
    out[1] = sr[0] * (1.0f / 1024.0f);
  }
}

// ------------------------------------------------------------------ launch
extern "C" void kernel_launch(void* const* d_in, const int* in_sizes, int n_in,
                              void* d_out, int out_size, void* d_ws, size_t ws_size,
                              hipStream_t stream) {
  const float* features  = (const float*)d_in[0];
  const float* proposals = (const float*)d_in[1];
  const float* gt_boxes  = (const float*)d_in[2];
  const int*   gt_labels = (const int*)d_in[3];
  const float* gt_ell    = (const float*)d_in[4];
  const float* w1 = (const float*)d_in[5];
  const float* b1 = (const float*)d_in[6];
  const float* w2 = (const float*)d_in[7];
  const float* b2 = (const float*)d_in[8];
  const float* wc = (const float*)d_in[9];
  const float* bc = (const float*)d_in[10];
  const float* wr = (const float*)d_in[11];
  const float* br = (const float*)d_in[12];
  float* out = (float*)d_out;

  char* ws = (char*)d_ws;
  size_t off = 0;
  auto take = [&](size_t bytes) -> void* {
    void* p = ws + off;
    off = (off + bytes + 255) & ~(size_t)255;
    return p;
  };
  // region0 hosts featT (33.5 MB, dead after roialign) then P (14x4 MiB partials)
  float* P     = (float*)take((size_t)SPLITK1 * HID * HID * 4);        // 58.7 MB
  float* featT = P;                                                    // alias
  __hip_bfloat16* Xb  = (__hip_bfloat16*)take((size_t)NSEL * K1 * 2);  // 25.7 MB
  // Xb dead after GEMM1: Y aliases into it
  float* Y   = (float*)Xb;
  __hip_bfloat16* W1T = (__hip_bfloat16*)take((size_t)HID * K1 * 2);   // 25.7 MB
  __hip_bfloat16* W2T = (__hip_bfloat16*)take((size_t)HID * HID * 2);  // 2.1 MB
  __hip_bfloat16* H1b = (__hip_bfloat16*)take((size_t)NSEL * HID * 2); // 2.1 MB
  int*   matches   = (int*)take((size_t)B_IMG * NPROPS * 4);
  int*   plab      = (int*)take((size_t)B_IMG * NPROPS * 4);
  float* prio      = (float*)take((size_t)B_IMG * NPROPS * 4);
  float* sel_boxes = (float*)take((size_t)NSEL * 4 * 4);
  int*   sel_lab   = (int*)take((size_t)NSEL * 4);
  float* targets   = (float*)take((size_t)NSEL * 6 * 4);

  k_sample<<<B_IMG, 256, 0, stream>>>(proposals, gt_boxes, gt_labels, prio, plab, matches);
  k_transpose<<<dim3(HWF / 64, C_FEAT / 64, B_IMG), 256, 0, stream>>>(features, featT);
  k_castT<1><<<dim3(C_FEAT / 64, HID / 64, 49), 256, 0, stream>>>(w1, W1T, K1);
  k_castT<0><<<dim3(HID / 64, HID / 64, 1), 256, 0, stream>>>(w2, W2T, HID);
  k_select<<<dim3(NPROPS / 4, B_IMG), 256, 0, stream>>>(prio, proposals, gt_boxes,
                                                        matches, plab, gt_ell,
                                                        sel_boxes, sel_lab, targets);
  k_roialign<<<dim3(NSEL, POOL), 256, 0, stream>>>(featT, sel_boxes, Xb);

  // GEMM1: Xb(1024 x 12544) @ W1T^T, 256x128 tile, split-K=14 -> reduce+relu -> H1b
  k_mfma_gemm<256><<<dim3(8, 4, SPLITK1), 512, 0, stream>>>(Xb, W1T, P, K1, K1 / SPLITK1);
  k_reduce<SPLITK1><<<1024, 256, 0, stream>>>(P, b1, H1b);
  // GEMM2: H1b(1024x1024) @ W2T^T, 128x128 tile, split-K=8 -> fused reduce+relu+head
  k_mfma_gemm<128><<<dim3(8, 8, SPLITK2), 256, 0, stream>>>(H1b, W2T, P, HID, HID / SPLITK2);
  k_reduce_head<<<1024, 256, 0, stream>>>(P, b2, wc, bc, wr, br, Y);

  k_loss<<<1, 1024, 0, stream>>>(Y, sel_lab, targets, out);
}

// Round 7
// 300.993 us; speedup vs baseline: 1.2430x; 1.0480x over previous
//
#include <hip/hip_runtime.h>
#include <hip/hip_bf16.h>
#include <math.h>

#define B_IMG   2
#define N_PROP  2000
#define N_GT    16
#define NPROPS  2016        // N_PROP + N_GT
#define C_FEAT  256
#define H_FEAT  128
#define W_FEAT  128
#define HWF     (H_FEAT*W_FEAT)
#define POOL    7
#define BPI     512
#define NPOSMAX 128
#define NSEL    (B_IMG*BPI)     // 1024
#define K1      (C_FEAT*POOL*POOL)  // 12544
#define HID     1024
#define NHEAD   14              // 2 logits + 12 reg
#define SPLITK1 14              // KC = 896 = 28*32
#define SPLITK2 4               // KC = 256 = 8*32

typedef short bf16x8f __attribute__((ext_vector_type(8)));   // 8 bf16 = 4 VGPRs
typedef float f32x4f  __attribute__((ext_vector_type(4)));
typedef short short4v __attribute__((ext_vector_type(4)));

// ---------------------------------------------------------------- threefry
__device__ __forceinline__ void threefry2x32(unsigned k0, unsigned k1,
                                             unsigned& x0, unsigned& x1) {
  unsigned ks[3] = {k0, k1, k0 ^ k1 ^ 0x1BD11BDAu};
  const int R0[4] = {13, 15, 26, 6};
  const int R1[4] = {17, 29, 16, 24};
  x0 += ks[0]; x1 += ks[1];
#pragma unroll
  for (int g = 0; g < 5; g++) {
    const int* rot = (g & 1) ? R1 : R0;
#pragma unroll
    for (int r = 0; r < 4; r++) {
      x0 += x1;
      x1 = (x1 << rot[r]) | (x1 >> (32 - rot[r]));
      x1 ^= x0;
    }
    x0 += ks[(g + 1) % 3];
    x1 += ks[(g + 2) % 3] + (unsigned)(g + 1);
  }
}

// ---------------------------------------- sampling: rand + match + priorities
__global__ __launch_bounds__(256) void k_sample(const float* __restrict__ proposals,
                                                const float* __restrict__ gt_boxes,
                                                const int* __restrict__ gt_labels,
                                                float* __restrict__ prio,
                                                int* __restrict__ plab,
                                                int* __restrict__ matches) {
  __shared__ float rs[NPROPS];
  __shared__ short pos_i[NPROPS];
  __shared__ float pos_r[NPROPS];
  __shared__ float gtb[N_GT * 4];
  __shared__ int   gtl[N_GT];
  __shared__ int   cnt;
  int b = blockIdx.x;
  int tid = threadIdx.x;
  int base = b * NPROPS;
  if (tid == 0) cnt = 0;
  if (tid < N_GT * 4) gtb[tid] = gt_boxes[b * N_GT * 4 + tid];
  if (tid < N_GT) gtl[tid] = gt_labels[b * N_GT + tid];
  __syncthreads();
  for (int i = tid; i < NPROPS; i += 256) {
    unsigned x0 = 0u, x1 = (unsigned)(base + i);
    threefry2x32(0u, 42u, x0, x1);
    unsigned bits = x0 ^ x1;
    float r = __uint_as_float((bits >> 9) | 0x3F800000u) - 1.0f;
    rs[i] = r;
    float p0, p1, p2, p3;
    if (i < N_PROP) {
      const float4 v = *(const float4*)(proposals + ((size_t)b * N_PROP + i) * 4);
      p0 = v.x; p1 = v.y; p2 = v.z; p3 = v.w;
    } else {
      const float* g = &gtb[(i - N_PROP) * 4];
      p0 = g[0]; p1 = g[1]; p2 = g[2]; p3 = g[3];
    }
    float a2 = (p2 - p0) * (p3 - p1);
    float best = -1.0f; int bg = 0;
#pragma unroll
    for (int g = 0; g < N_GT; g++) {
      float g0 = gtb[g * 4], g1 = gtb[g * 4 + 1], g2 = gtb[g * 4 + 2], g3 = gtb[g * 4 + 3];
      float a1 = (g2 - g0) * (g3 - g1);
      float wx = fmaxf(fminf(g2, p2) - fmaxf(g0, p0), 0.0f);
      float wy = fmaxf(fminf(g3, p3) - fmaxf(g1, p1), 0.0f);
      float inter = wx * wy;
      float iou = inter / (a1 + a2 - inter);
      if (iou > best) { best = iou; bg = g; }
    }
    matches[base + i] = bg;
    int lab = (best < 0.5f) ? 0 : gtl[bg];
    plab[base + i] = lab;
    if (lab > 0) {
      int s = atomicAdd(&cnt, 1);
      pos_i[s] = (short)i; pos_r[s] = r;
    }
  }
  __syncthreads();
  int P = cnt;
  for (int s = tid; s < P; s += 256) {
    int i = pos_i[s]; float ri = pos_r[s];
    int ch = 0;
    for (int j = 0; j < P; j++) {
      float rj = pos_r[j]; int ij = pos_i[j];
      ch += (rj > ri || (rj == ri && ij < i)) ? 1 : 0;
    }
    rs[i] = (ch < NPOSMAX) ? (ri + 2.0f) : -1000000000.0f;
  }
  __syncthreads();
  for (int i = tid; i < NPROPS; i += 256) prio[base + i] = rs[i];
}

// ------------------------------------------------- select + gather + encode
// wave-per-candidate: grid (NPROPS/4, B_IMG), 4 waves/block.
__global__ __launch_bounds__(256) void k_select(const float* __restrict__ prio,
    const float* __restrict__ proposals, const float* __restrict__ gt_boxes,
    const int* __restrict__ matches, const int* __restrict__ plab,
    const float* __restrict__ gt_ell,
    float* __restrict__ sel_boxes, int* __restrict__ sel_labels,
    float* __restrict__ targets) {
  int tid = threadIdx.x;
  int wave = tid >> 6, lane = tid & 63;
  int b = blockIdx.y;
  int base = b * NPROPS;
  int i = blockIdx.x * 4 + wave;       // 0..2015
  float pi = prio[base + i];
  int rank = 0;
  for (int j = lane; j < NPROPS; j += 64) {
    float pj = prio[base + j];
    rank += (pj > pi || (pj == pi && j < i)) ? 1 : 0;
  }
#pragma unroll
  for (int off = 32; off > 0; off >>= 1) rank += __shfl_down(rank, off);
  if (lane != 0 || rank >= BPI) return;
  int slot = b * BPI + rank;
  float p0, p1, p2, p3;
  if (i < N_PROP) {
    const float* p = proposals + ((size_t)b * N_PROP + i) * 4;
    p0 = p[0]; p1 = p[1]; p2 = p[2]; p3 = p[3];
  } else {
    const float* p = gt_boxes + ((size_t)b * N_GT + (i - N_PROP)) * 4;
    p0 = p[0]; p1 = p[1]; p2 = p[2]; p3 = p[3];
  }
  sel_boxes[slot * 4 + 0] = p0;
  sel_boxes[slot * 4 + 1] = p1;
  sel_boxes[slot * 4 + 2] = p2;
  sel_boxes[slot * 4 + 3] = p3;
  int lb = plab[base + i];
  sel_labels[slot] = lb;
  int m = matches[base + i];
  const float* e = gt_ell + ((size_t)b * N_GT + m) * 5;
  float ea = e[0], eb = e[1], ex = e[2], ey = e[3], eth = e[4];
  float w = fmaxf(p2 - p0, 1.0f), h = fmaxf(p3 - p1, 1.0f);
  float cx = 0.5f * (p0 + p2), cy = 0.5f * (p1 + p3);
  float* t = targets + (size_t)slot * 6;
  t[0] = (ex - cx) / w;
  t[1] = (ey - cy) / h;
  t[2] = logf(fmaxf(2.0f * ea, 0.001f) / w);
  t[3] = logf(fmaxf(2.0f * eb, 0.001f) / h);
  t[4] = sinf(2.0f * eth);
  t[5] = cosf(2.0f * eth);
}

// ------------------------------------------------------------- NCHW -> NHWC (bf16)
__global__ __launch_bounds__(256) void k_transpose(const float* __restrict__ in,
                                                   __hip_bfloat16* __restrict__ out) {
  __shared__ float tile[64][65];
  int b = blockIdx.z;
  int s0 = blockIdx.x * 64;   // hw
  int c0 = blockIdx.y * 64;   // channel
  const float* src = in + (size_t)b * C_FEAT * HWF;
  __hip_bfloat16* dst = out + (size_t)b * HWF * C_FEAT;
  int t = threadIdx.x;
  int hw4 = (t & 15) * 4;
  int cr  = t >> 4;
#pragma unroll
  for (int p = 0; p < 4; p++) {
    int c = cr + p * 16;
    float4 v = *(const float4*)(src + (size_t)(c0 + c) * HWF + s0 + hw4);
    tile[hw4 + 0][c] = v.x;
    tile[hw4 + 1][c] = v.y;
    tile[hw4 + 2][c] = v.z;
    tile[hw4 + 3][c] = v.w;
  }
  __syncthreads();
  int c4 = (t & 15) * 4;
  int hr = t >> 4;
#pragma unroll
  for (int p = 0; p < 4; p++) {
    int hw = hr + p * 16;
    __hip_bfloat16 o[4] = {__float2bfloat16(tile[hw][c4]), __float2bfloat16(tile[hw][c4 + 1]),
                           __float2bfloat16(tile[hw][c4 + 2]), __float2bfloat16(tile[hw][c4 + 3])};
    *(short4v*)(dst + (size_t)(s0 + hw) * C_FEAT + c0 + c4) = *(short4v*)o;
  }
}

// ------------------- fast weight cast: fp32 [K][N] -> bf16 [N][K] (64x64 tiles)
template <int PERM>
__global__ __launch_bounds__(256) void k_castT(const float* __restrict__ W,
                                               __hip_bfloat16* __restrict__ WT,
                                               int Kout) {
  __shared__ float t[64][65];
  int p  = blockIdx.z;
  int c0 = blockIdx.x * 64;
  int n0 = blockIdx.y * 64;
  int tx = threadIdx.x & 63, ty = threadIdx.x >> 6;
#pragma unroll
  for (int i = ty; i < 64; i += 4) {
    int krow = PERM ? ((c0 + i) * 49 + p) : (c0 + i);
    t[i][tx] = W[(size_t)krow * HID + n0 + tx];
  }
  __syncthreads();
#pragma unroll
  for (int i = ty; i < 64; i += 4) {
    int kx = PERM ? (p * 256 + c0 + tx) : (c0 + tx);
    WT[(size_t)(n0 + i) * Kout + kx] = __float2bfloat16(t[tx][i]);
  }
}

// ---------------------------------------------------------------- roi align (bf16 feat)
__global__ __launch_bounds__(256) void k_roialign(const __hip_bfloat16* __restrict__ featT,
                                                  const float* __restrict__ sel_boxes,
                                                  __hip_bfloat16* __restrict__ X) {
  int n = blockIdx.x;
  int py = blockIdx.y;
  int t = threadIdx.x;
  int lane = t & 63, sub = t >> 6;
  int c = lane << 2;
  int b = n >> 9;
  const float* bx = sel_boxes + (size_t)n * 4;
  float x1 = bx[0] * 0.125f, y1 = bx[1] * 0.125f;
  float x2 = bx[2] * 0.125f, y2 = bx[3] * 0.125f;
  float bw = fmaxf(x2 - x1, 1.0f) / 7.0f;
  float bh = fmaxf(y2 - y1, 1.0f) / 7.0f;
  const __hip_bfloat16* base = featT + (size_t)b * HWF * C_FEAT;
  int y0A[2]; float lyA[2];
#pragma unroll
  for (int sy = 0; sy < 2; sy++) {
    float off = ((float)(py * 2 + sy) + 0.5f) * 0.5f;
    float ys = fminf(fmaxf(y1 + off * bh, 0.0f), 127.0f);
    int y0 = (int)fminf(fmaxf(floorf(ys), 0.0f), 126.0f);
    y0A[sy] = y0; lyA[sy] = ys - (float)y0;
  }
#pragma unroll
  for (int pass = 0; pass < 2; pass++) {
    int px = sub + (pass << 2);
    if (px >= 7) break;
    float acc[4] = {0.0f, 0.0f, 0.0f, 0.0f};
#pragma unroll
    for (int sx = 0; sx < 2; sx++) {
      float off = ((float)(px * 2 + sx) + 0.5f) * 0.5f;
      float xs = fminf(fmaxf(x1 + off * bw, 0.0f), 127.0f);
      int x0 = (int)fminf(fmaxf(floorf(xs), 0.0f), 126.0f);
      float lx = xs - (float)x0;
#pragma unroll
      for (int sy = 0; sy < 2; sy++) {
        int y0 = y0A[sy]; float ly = lyA[sy];
        const __hip_bfloat16* p = base + ((size_t)(y0 * W_FEAT + x0)) * C_FEAT + c;
        short4v s00 = *(const short4v*)p;
        short4v s01 = *(const short4v*)(p + C_FEAT);
        short4v s10 = *(const short4v*)(p + W_FEAT * C_FEAT);
        short4v s11 = *(const short4v*)(p + W_FEAT * C_FEAT + C_FEAT);
        float w00 = (1.0f - ly) * (1.0f - lx), w01 = (1.0f - ly) * lx;
        float w10 = ly * (1.0f - lx), w11 = ly * lx;
#pragma unroll
        for (int q = 0; q < 4; q++) {
          float v00 = __uint_as_float(((unsigned)(unsigned short)s00[q]) << 16);
          float v01 = __uint_as_float(((unsigned)(unsigned short)s01[q]) << 16);
          float v10 = __uint_as_float(((unsigned)(unsigned short)s10[q]) << 16);
          float v11 = __uint_as_float(((unsigned)(unsigned short)s11[q]) << 16);
          acc[q] += v00 * w00 + v01 * w01 + v10 * w10 + v11 * w11;
        }
      }
    }
    __hip_bfloat16 o[4] = {__float2bfloat16(acc[0] * 0.25f), __float2bfloat16(acc[1] * 0.25f),
                           __float2bfloat16(acc[2] * 0.25f), __float2bfloat16(acc[3] * 0.25f)};
    *(short4v*)&X[(size_t)n * K1 + (size_t)(py * 7 + px) * C_FEAT + c] = *(short4v*)o;
  }
}

// ------------------------------------------------------- bf16 MFMA GEMM (split-K)
// AM = A-tile rows (256 or 128); B-tile = 128 cols; BK=32; blockDim = AM*2.
// XOR-swizzled LDS chunks: row r's global 16B-chunk g at slot g^(r&3).
__device__ __forceinline__ void gld_lds16(const __hip_bfloat16* g, __hip_bfloat16* l) {
  __builtin_amdgcn_global_load_lds(
      (const __attribute__((address_space(1))) void*)g,
      (__attribute__((address_space(3))) void*)l, 16, 0, 0);
}

template <int AM>
__global__ __launch_bounds__(AM * 2) void k_mfma_gemm(const __hip_bfloat16* __restrict__ A,
                                                      const __hip_bfloat16* __restrict__ BT,
                                                      float* __restrict__ P,
                                                      int K, int KC) {
  const int TPB = AM * 2;
  __shared__ __align__(16) __hip_bfloat16 As[AM * 32];
  __shared__ __align__(16) __hip_bfloat16 Bs[128 * 32];
  int tid = threadIdx.x;
  int n0 = blockIdx.x * 128, m0 = blockIdx.y * AM;
  int kz = blockIdx.z;
  int kbeg = kz * KC;
  int srow = tid >> 2;                       // 0..TPB/4-1
  int scs  = tid & 3;                        // LDS chunk slot
  int sg   = scs ^ (srow & 3);               // global chunk staged by this lane
  int scol = sg << 3;
  int wave = tid >> 6, lane = tid & 63;
  const int WMW = AM / 64;
  int wm = (wave % WMW) * 64, wn = (wave / WMW) * 64;
  int lm = lane & 15, quad = lane >> 4;
  int fco = ((quad ^ (lm & 3)) << 3);        // swizzled fragment chunk offset
  f32x4f acc[4][4] = {};
  for (int k0 = kbeg; k0 < kbeg + KC; k0 += 32) {
    __syncthreads();
#pragma unroll
    for (int r0 = 0; r0 < AM; r0 += TPB / 4)
      gld_lds16(A + (size_t)(m0 + r0 + srow) * K + k0 + scol, &As[(r0 + srow) * 32 + scs * 8]);
#pragma unroll
    for (int r0 = 0; r0 < 128; r0 += TPB / 4)
      gld_lds16(BT + (size_t)(n0 + r0 + srow) * K + k0 + scol, &Bs[(r0 + srow) * 32 + scs * 8]);
    __syncthreads();
    bf16x8f af[4], bf[4];
#pragma unroll
    for (int i = 0; i < 4; i++)
      af[i] = *(const bf16x8f*)&As[(wm + i * 16 + lm) * 32 + fco];
#pragma unroll
    for (int j = 0; j < 4; j++)
      bf[j] = *(const bf16x8f*)&Bs[(wn + j * 16 + lm) * 32 + fco];
#pragma unroll
    for (int i = 0; i < 4; i++)
#pragma unroll
      for (int j = 0; j < 4; j++)
        acc[i][j] = __builtin_amdgcn_mfma_f32_16x16x32_bf16(af[i], bf[j], acc[i][j], 0, 0, 0);
  }
  // C/D layout: col = lane&15, row = quad*4 + reg
#pragma unroll
  for (int i = 0; i < 4; i++)
#pragma unroll
    for (int j = 0; j < 4; j++) {
      float* base = P + ((size_t)kz << 20)
                      + (size_t)(m0 + wm + i * 16 + quad * 4) * HID
                      + (n0 + wn + j * 16 + lm);
#pragma unroll
      for (int r = 0; r < 4; r++) base[(size_t)r * HID] = acc[i][j][r];
    }
}

// reduce split-K partials + bias + relu -> bf16 (after GEMM1)
template <int Z>
__global__ __launch_bounds__(256) void k_reduce(const float* __restrict__ P,
                                                const float* __restrict__ bias,
                                                __hip_bfloat16* __restrict__ O) {
  int idx4 = blockIdx.x * 256 + threadIdx.x;
  int m = idx4 >> 8;
  int n4 = (idx4 & 255) << 2;
  float4 s = *(const float4*)(bias + n4);
#pragma unroll
  for (int z = 0; z < Z; z++) {
    float4 p = *(const float4*)(P + ((size_t)z << 20) + ((size_t)m << 10) + n4);
    s.x += p.x; s.y += p.y; s.z += p.z; s.w += p.w;
  }
  __hip_bfloat16 t[4] = {__float2bfloat16(fmaxf(s.x, 0.0f)), __float2bfloat16(fmaxf(s.y, 0.0f)),
                         __float2bfloat16(fmaxf(s.z, 0.0f)), __float2bfloat16(fmaxf(s.w, 0.0f))};
  *(short4v*)(O + ((size_t)m << 10) + n4) = *(short4v*)t;
}

// ---------------------- reduce GEMM2 partials + bias + relu + head, fused.
__global__ __launch_bounds__(256) void k_reduce_head(const float* __restrict__ P,
                                                     const float* __restrict__ bias,
                                                     const float* __restrict__ wc,
                                                     const float* __restrict__ bc,
                                                     const float* __restrict__ wr,
                                                     const float* __restrict__ br,
                                                     float* __restrict__ Y) {
  __shared__ float part[4][NHEAD];
  int m = blockIdx.x, tid = threadIdx.x;
  int n4 = tid << 2;
  float4 s = *(const float4*)(bias + n4);
#pragma unroll
  for (int z = 0; z < SPLITK2; z++) {
    float4 p = *(const float4*)(P + ((size_t)z << 20) + ((size_t)m << 10) + n4);
    s.x += p.x; s.y += p.y; s.z += p.z; s.w += p.w;
  }
  float hv4[4] = {fmaxf(s.x, 0.0f), fmaxf(s.y, 0.0f), fmaxf(s.z, 0.0f), fmaxf(s.w, 0.0f)};
  float a[NHEAD];
#pragma unroll
  for (int j = 0; j < NHEAD; j++) a[j] = 0.0f;
#pragma unroll
  for (int q = 0; q < 4; q++) {
    int kk = n4 + q;
    float hv = hv4[q];
    float2 wcv = *(const float2*)(wc + kk * 2);
    float4 w0 = *(const float4*)(wr + kk * 12);
    float4 w1 = *(const float4*)(wr + kk * 12 + 4);
    float4 w2 = *(const float4*)(wr + kk * 12 + 8);
    a[0] += hv * wcv.x;  a[1] += hv * wcv.y;
    a[2] += hv * w0.x;   a[3] += hv * w0.y;  a[4] += hv * w0.z;  a[5] += hv * w0.w;
    a[6] += hv * w1.x;   a[7] += hv * w1.y;  a[8] += hv * w1.z;  a[9] += hv * w1.w;
    a[10] += hv * w2.x;  a[11] += hv * w2.y; a[12] += hv * w2.z; a[13] += hv * w2.w;
  }
#pragma unroll
  for (int j = 0; j < NHEAD; j++)
#pragma unroll
    for (int off = 32; off > 0; off >>= 1) a[j] += __shfl_down(a[j], off);
  int wave = tid >> 6, lane = tid & 63;
  if (lane == 0)
#pragma unroll
    for (int j = 0; j < NHEAD; j++) part[wave][j] = a[j];
  __syncthreads();
  if (tid < NHEAD) {
    float v = part[0][tid] + part[1][tid] + part[2][tid] + part[3][tid];
    Y[(size_t)m * NHEAD + tid] = v + ((tid < 2) ? bc[tid] : br[tid - 2]);
  }
}

// ------------------------------------------------------------------- losses
__global__ __launch_bounds__(1024) void k_loss(const float* __restrict__ Y,
                                               const int* __restrict__ sel_labels,
                                               const float* __restrict__ T,
                                               float* __restrict__ out) {
  __shared__ float sc[1024];
  __shared__ float sr[1024];
  int n = threadIdx.x;
  float l0 = Y[(size_t)n * NHEAD + 0], l1 = Y[(size_t)n * NHEAD + 1];
  int lb = sel_labels[n];
  float mx = fmaxf(l0, l1);
  float lse = mx + logf(expf(l0 - mx) + expf(l1 - mx));
  float ce = lse - (lb ? l1 : l0);
  float reg = 0.0f;
  if (lb > 0) {
    const float beta = 1.0f / 9.0f;
    const float* pr = Y + (size_t)n * NHEAD + 2 + lb * 6;
    const float* t = T + (size_t)n * 6;
#pragma unroll
    for (int j = 0; j < 6; j++) {
      float d = fabsf(pr[j] - t[j]);
      reg += (d < beta) ? (0.5f * d * d / beta) : (d - 0.5f * beta);
    }
  }
  sc[n] = ce; sr[n] = reg;
  __syncthreads();
  for (int s = 512; s > 0; s >>= 1) {
    if (n < s) { sc[n] += sc[n + s]; sr[n] += sr[n + s]; }
    __syncthreads();
  }
  if (n == 0) {
    out[0] = sc[0] * (1.0f / 1024.0f);
    out[1] = sr[0] * (1.0f / 1024.0f);
  }
}

// ------------------------------------------------------------------ launch
extern "C" void kernel_launch(void* const* d_in, const int* in_sizes, int n_in,
                              void* d_out, int out_size, void* d_ws, size_t ws_size,
                              hipStream_t stream) {
  const float* features  = (const float*)d_in[0];
  const float* proposals = (const float*)d_in[1];
  const float* gt_boxes  = (const float*)d_in[2];
  const int*   gt_labels = (const int*)d_in[3];
  const float* gt_ell    = (const float*)d_in[4];
  const float* w1 = (const float*)d_in[5];
  const float* b1 = (const float*)d_in[6];
  const float* w2 = (const float*)d_in[7];
  const float* b2 = (const float*)d_in[8];
  const float* wc = (const float*)d_in[9];
  const float* bc = (const float*)d_in[10];
  const float* wr = (const float*)d_in[11];
  const float* br = (const float*)d_in[12];
  float* out = (float*)d_out;

  char* ws = (char*)d_ws;
  size_t off = 0;
  auto take = [&](size_t bytes) -> void* {
    void* p = ws + off;
    off = (off + bytes + 255) & ~(size_t)255;
    return p;
  };
  // region0 hosts featT (bf16, 16.7 MB, dead after roialign) then P (14x4 MiB partials)
  float* P = (float*)take((size_t)SPLITK1 * HID * HID * 4);            // 58.7 MB
  __hip_bfloat16* featT = (__hip_bfloat16*)P;                          // alias
  __hip_bfloat16* Xb  = (__hip_bfloat16*)take((size_t)NSEL * K1 * 2);  // 25.7 MB
  // Xb dead after GEMM1: Y aliases into it
  float* Y   = (float*)Xb;
  __hip_bfloat16* W1T = (__hip_bfloat16*)take((size_t)HID * K1 * 2);   // 25.7 MB
  __hip_bfloat16* W2T = (__hip_bfloat16*)take((size_t)HID * HID * 2);  // 2.1 MB
  __hip_bfloat16* H1b = (__hip_bfloat16*)take((size_t)NSEL * HID * 2); // 2.1 MB
  int*   matches   = (int*)take((size_t)B_IMG * NPROPS * 4);
  int*   plab      = (int*)take((size_t)B_IMG * NPROPS * 4);
  float* prio      = (float*)take((size_t)B_IMG * NPROPS * 4);
  float* sel_boxes = (float*)take((size_t)NSEL * 4 * 4);
  int*   sel_lab   = (int*)take((size_t)NSEL * 4);
  float* targets   = (float*)take((size_t)NSEL * 6 * 4);

  k_sample<<<B_IMG, 256, 0, stream>>>(proposals, gt_boxes, gt_labels, prio, plab, matches);
  k_transpose<<<dim3(HWF / 64, C_FEAT / 64, B_IMG), 256, 0, stream>>>(features, featT);
  k_castT<1><<<dim3(C_FEAT / 64, HID / 64, 49), 256, 0, stream>>>(w1, W1T, K1);
  k_castT<0><<<dim3(HID / 64, HID / 64, 1), 256, 0, stream>>>(w2, W2T, HID);
  k_select<<<dim3(NPROPS / 4, B_IMG), 256, 0, stream>>>(prio, proposals, gt_boxes,
                                                        matches, plab, gt_ell,
                                                        sel_boxes, sel_lab, targets);
  k_roialign<<<dim3(NSEL, POOL), 256, 0, stream>>>(featT, sel_boxes, Xb);

  // GEMM1: Xb(1024 x 12544) @ W1T^T, 256x128 tile, split-K=14 -> reduce+relu -> H1b
  k_mfma_gemm<256><<<dim3(8, 4, SPLITK1), 512, 0, stream>>>(Xb, W1T, P, K1, K1 / SPLITK1);
  k_reduce<SPLITK1><<<1024, 256, 0, stream>>>(P, b1, H1b);
  // GEMM2: H1b(1024x1024) @ W2T^T, 128x128 tile, split-K=4 -> fused reduce+relu+head
  k_mfma_gemm<128><<<dim3(8, 8, SPLITK2), 256, 0, stream>>>(H1b, W2T, P, HID, HID / SPLITK2);
  k_reduce_head<<<1024, 256, 0, stream>>>(P, b2, wc, bc, wr, br, Y);

  k_loss<<<1, 1024, 0, stream>>>(Y, sel_lab, targets, out);
}

// Round 8
// 287.324 us; speedup vs baseline: 1.3021x; 1.0476x over previous
//
#include <hip/hip_runtime.h>
#include <hip/hip_bf16.h>
#include <math.h>

#define B_IMG   2
#define N_PROP  2000
#define N_GT    16
#define NPROPS  2016        // N_PROP + N_GT
#define C_FEAT  256
#define H_FEAT  128
#define W_FEAT  128
#define HWF     (H_FEAT*W_FEAT)
#define POOL    7
#define BPI     512
#define NPOSMAX 128
#define NSEL    (B_IMG*BPI)     // 1024
#define K1      (C_FEAT*POOL*POOL)  // 12544
#define K1P     12800           // K1 padded to 16*800 (800 = 25*32)
#define HID     1024
#define NHEAD   14              // 2 logits + 12 reg
#define SPLITK1 16              // KC = 800
#define SPLITK2 4               // KC = 256

typedef short bf16x8f __attribute__((ext_vector_type(8)));   // 8 bf16 = 4 VGPRs
typedef float f32x4f  __attribute__((ext_vector_type(4)));
typedef short short4v __attribute__((ext_vector_type(4)));

// ---------------------------------------------------------------- threefry
__device__ __forceinline__ void threefry2x32(unsigned k0, unsigned k1,
                                             unsigned& x0, unsigned& x1) {
  unsigned ks[3] = {k0, k1, k0 ^ k1 ^ 0x1BD11BDAu};
  const int R0[4] = {13, 15, 26, 6};
  const int R1[4] = {17, 29, 16, 24};
  x0 += ks[0]; x1 += ks[1];
#pragma unroll
  for (int g = 0; g < 5; g++) {
    const int* rot = (g & 1) ? R1 : R0;
#pragma unroll
    for (int r = 0; r < 4; r++) {
      x0 += x1;
      x1 = (x1 << rot[r]) | (x1 >> (32 - rot[r]));
      x1 ^= x0;
    }
    x0 += ks[(g + 1) % 3];
    x1 += ks[(g + 2) % 3] + (unsigned)(g + 1);
  }
}

// ---------------------------------------- sampling: rand + match + priorities
__global__ __launch_bounds__(256) void k_sample(const float* __restrict__ proposals,
                                                const float* __restrict__ gt_boxes,
                                                const int* __restrict__ gt_labels,
                                                float* __restrict__ prio,
                                                int* __restrict__ plab,
                                                int* __restrict__ matches) {
  __shared__ float rs[NPROPS];
  __shared__ short pos_i[NPROPS];
  __shared__ float pos_r[NPROPS];
  __shared__ float gtb[N_GT * 4];
  __shared__ int   gtl[N_GT];
  __shared__ int   cnt;
  int b = blockIdx.x;
  int tid = threadIdx.x;
  int base = b * NPROPS;
  if (tid == 0) cnt = 0;
  if (tid < N_GT * 4) gtb[tid] = gt_boxes[b * N_GT * 4 + tid];
  if (tid < N_GT) gtl[tid] = gt_labels[b * N_GT + tid];
  __syncthreads();
  for (int i = tid; i < NPROPS; i += 256) {
    unsigned x0 = 0u, x1 = (unsigned)(base + i);
    threefry2x32(0u, 42u, x0, x1);
    unsigned bits = x0 ^ x1;
    float r = __uint_as_float((bits >> 9) | 0x3F800000u) - 1.0f;
    rs[i] = r;
    float p0, p1, p2, p3;
    if (i < N_PROP) {
      const float4 v = *(const float4*)(proposals + ((size_t)b * N_PROP + i) * 4);
      p0 = v.x; p1 = v.y; p2 = v.z; p3 = v.w;
    } else {
      const float* g = &gtb[(i - N_PROP) * 4];
      p0 = g[0]; p1 = g[1]; p2 = g[2]; p3 = g[3];
    }
    float a2 = (p2 - p0) * (p3 - p1);
    float best = -1.0f; int bg = 0;
#pragma unroll
    for (int g = 0; g < N_GT; g++) {
      float g0 = gtb[g * 4], g1 = gtb[g * 4 + 1], g2 = gtb[g * 4 + 2], g3 = gtb[g * 4 + 3];
      float a1 = (g2 - g0) * (g3 - g1);
      float wx = fmaxf(fminf(g2, p2) - fmaxf(g0, p0), 0.0f);
      float wy = fmaxf(fminf(g3, p3) - fmaxf(g1, p1), 0.0f);
      float inter = wx * wy;
      float iou = inter / (a1 + a2 - inter);
      if (iou > best) { best = iou; bg = g; }
    }
    matches[base + i] = bg;
    int lab = (best < 0.5f) ? 0 : gtl[bg];
    plab[base + i] = lab;
    if (lab > 0) {
      int s = atomicAdd(&cnt, 1);
      pos_i[s] = (short)i; pos_r[s] = r;
    }
  }
  __syncthreads();
  int P = cnt;
  for (int s = tid; s < P; s += 256) {
    int i = pos_i[s]; float ri = pos_r[s];
    int ch = 0;
    for (int j = 0; j < P; j++) {
      float rj = pos_r[j]; int ij = pos_i[j];
      ch += (rj > ri || (rj == ri && ij < i)) ? 1 : 0;
    }
    rs[i] = (ch < NPOSMAX) ? (ri + 2.0f) : -1000000000.0f;
  }
  __syncthreads();
  for (int i = tid; i < NPROPS; i += 256) prio[base + i] = rs[i];
}

// ------------------------------------------------- select + gather + encode
__global__ __launch_bounds__(256) void k_select(const float* __restrict__ prio,
    const float* __restrict__ proposals, const float* __restrict__ gt_boxes,
    const int* __restrict__ matches, const int* __restrict__ plab,
    const float* __restrict__ gt_ell,
    float* __restrict__ sel_boxes, int* __restrict__ sel_labels,
    float* __restrict__ targets) {
  int tid = threadIdx.x;
  int wave = tid >> 6, lane = tid & 63;
  int b = blockIdx.y;
  int base = b * NPROPS;
  int i = blockIdx.x * 4 + wave;       // 0..2015
  float pi = prio[base + i];
  int rank = 0;
  for (int j = lane; j < NPROPS; j += 64) {
    float pj = prio[base + j];
    rank += (pj > pi || (pj == pi && j < i)) ? 1 : 0;
  }
#pragma unroll
  for (int off = 32; off > 0; off >>= 1) rank += __shfl_down(rank, off);
  if (lane != 0 || rank >= BPI) return;
  int slot = b * BPI + rank;
  float p0, p1, p2, p3;
  if (i < N_PROP) {
    const float* p = proposals + ((size_t)b * N_PROP + i) * 4;
    p0 = p[0]; p1 = p[1]; p2 = p[2]; p3 = p[3];
  } else {
    const float* p = gt_boxes + ((size_t)b * N_GT + (i - N_PROP)) * 4;
    p0 = p[0]; p1 = p[1]; p2 = p[2]; p3 = p[3];
  }
  sel_boxes[slot * 4 + 0] = p0;
  sel_boxes[slot * 4 + 1] = p1;
  sel_boxes[slot * 4 + 2] = p2;
  sel_boxes[slot * 4 + 3] = p3;
  int lb = plab[base + i];
  sel_labels[slot] = lb;
  int m = matches[base + i];
  const float* e = gt_ell + ((size_t)b * N_GT + m) * 5;
  float ea = e[0], eb = e[1], ex = e[2], ey = e[3], eth = e[4];
  float w = fmaxf(p2 - p0, 1.0f), h = fmaxf(p3 - p1, 1.0f);
  float cx = 0.5f * (p0 + p2), cy = 0.5f * (p1 + p3);
  float* t = targets + (size_t)slot * 6;
  t[0] = (ex - cx) / w;
  t[1] = (ey - cy) / h;
  t[2] = logf(fmaxf(2.0f * ea, 0.001f) / w);
  t[3] = logf(fmaxf(2.0f * eb, 0.001f) / h);
  t[4] = sinf(2.0f * eth);
  t[5] = cosf(2.0f * eth);
}

// ------------------------------------------------------------- NCHW -> NHWC (bf16)
__global__ __launch_bounds__(256) void k_transpose(const float* __restrict__ in,
                                                   __hip_bfloat16* __restrict__ out) {
  __shared__ float tile[64][65];
  int b = blockIdx.z;
  int s0 = blockIdx.x * 64;   // hw
  int c0 = blockIdx.y * 64;   // channel
  const float* src = in + (size_t)b * C_FEAT * HWF;
  __hip_bfloat16* dst = out + (size_t)b * HWF * C_FEAT;
  int t = threadIdx.x;
  int hw4 = (t & 15) * 4;
  int cr  = t >> 4;
#pragma unroll
  for (int p = 0; p < 4; p++) {
    int c = cr + p * 16;
    float4 v = *(const float4*)(src + (size_t)(c0 + c) * HWF + s0 + hw4);
    tile[hw4 + 0][c] = v.x;
    tile[hw4 + 1][c] = v.y;
    tile[hw4 + 2][c] = v.z;
    tile[hw4 + 3][c] = v.w;
  }
  __syncthreads();
  int c4 = (t & 15) * 4;
  int hr = t >> 4;
#pragma unroll
  for (int p = 0; p < 4; p++) {
    int hw = hr + p * 16;
    __hip_bfloat16 o[4] = {__float2bfloat16(tile[hw][c4]), __float2bfloat16(tile[hw][c4 + 1]),
                           __float2bfloat16(tile[hw][c4 + 2]), __float2bfloat16(tile[hw][c4 + 3])};
    *(short4v*)(dst + (size_t)(s0 + hw) * C_FEAT + c0 + c4) = *(short4v*)o;
  }
}

// ------------------- fast weight cast: fp32 [K][N] -> bf16 [N][Kout] (64x64 tiles)
template <int PERM>
__global__ __launch_bounds__(256) void k_castT(const float* __restrict__ W,
                                               __hip_bfloat16* __restrict__ WT,
                                               int Kout) {
  __shared__ float t[64][65];
  int p  = blockIdx.z;
  int c0 = blockIdx.x * 64;
  int n0 = blockIdx.y * 64;
  int tx = threadIdx.x & 63, ty = threadIdx.x >> 6;
#pragma unroll
  for (int i = ty; i < 64; i += 4) {
    int krow = PERM ? ((c0 + i) * 49 + p) : (c0 + i);
    t[i][tx] = W[(size_t)krow * HID + n0 + tx];
  }
  __syncthreads();
#pragma unroll
  for (int i = ty; i < 64; i += 4) {
    int kx = PERM ? (p * 256 + c0 + tx) : (c0 + tx);
    WT[(size_t)(n0 + i) * Kout + kx] = __float2bfloat16(t[tx][i]);
  }
}

// ----------------------------- zero the K-pad region of Xb and W1T (cols K1..K1P)
__global__ __launch_bounds__(256) void k_pad(__hip_bfloat16* __restrict__ Xb,
                                             __hip_bfloat16* __restrict__ W1T) {
  __hip_bfloat16* buf = blockIdx.y ? W1T : Xb;
  int t = blockIdx.x * 256 + threadIdx.x;   // 256 blocks * 256 thr * 4 = 262144
  int row = t >> 6;                         // 64 short4v per row pad
  int col4 = (t & 63) << 2;
  short4v z = {0, 0, 0, 0};
  *(short4v*)(buf + (size_t)row * K1P + K1 + col4) = z;
}

// ---------------------------------------------------------------- roi align (bf16 feat)
__global__ __launch_bounds__(256) void k_roialign(const __hip_bfloat16* __restrict__ featT,
                                                  const float* __restrict__ sel_boxes,
                                                  __hip_bfloat16* __restrict__ X) {
  int n = blockIdx.x;
  int py = blockIdx.y;
  int t = threadIdx.x;
  int lane = t & 63, sub = t >> 6;
  int c = lane << 2;
  int b = n >> 9;
  const float* bx = sel_boxes + (size_t)n * 4;
  float x1 = bx[0] * 0.125f, y1 = bx[1] * 0.125f;
  float x2 = bx[2] * 0.125f, y2 = bx[3] * 0.125f;
  float bw = fmaxf(x2 - x1, 1.0f) / 7.0f;
  float bh = fmaxf(y2 - y1, 1.0f) / 7.0f;
  const __hip_bfloat16* base = featT + (size_t)b * HWF * C_FEAT;
  int y0A[2]; float lyA[2];
#pragma unroll
  for (int sy = 0; sy < 2; sy++) {
    float off = ((float)(py * 2 + sy) + 0.5f) * 0.5f;
    float ys = fminf(fmaxf(y1 + off * bh, 0.0f), 127.0f);
    int y0 = (int)fminf(fmaxf(floorf(ys), 0.0f), 126.0f);
    y0A[sy] = y0; lyA[sy] = ys - (float)y0;
  }
#pragma unroll
  for (int pass = 0; pass < 2; pass++) {
    int px = sub + (pass << 2);
    if (px >= 7) break;
    float acc[4] = {0.0f, 0.0f, 0.0f, 0.0f};
#pragma unroll
    for (int sx = 0; sx < 2; sx++) {
      float off = ((float)(px * 2 + sx) + 0.5f) * 0.5f;
      float xs = fminf(fmaxf(x1 + off * bw, 0.0f), 127.0f);
      int x0 = (int)fminf(fmaxf(floorf(xs), 0.0f), 126.0f);
      float lx = xs - (float)x0;
#pragma unroll
      for (int sy = 0; sy < 2; sy++) {
        int y0 = y0A[sy]; float ly = lyA[sy];
        const __hip_bfloat16* p = base + ((size_t)(y0 * W_FEAT + x0)) * C_FEAT + c;
        short4v s00 = *(const short4v*)p;
        short4v s01 = *(const short4v*)(p + C_FEAT);
        short4v s10 = *(const short4v*)(p + W_FEAT * C_FEAT);
        short4v s11 = *(const short4v*)(p + W_FEAT * C_FEAT + C_FEAT);
        float w00 = (1.0f - ly) * (1.0f - lx), w01 = (1.0f - ly) * lx;
        float w10 = ly * (1.0f - lx), w11 = ly * lx;
#pragma unroll
        for (int q = 0; q < 4; q++) {
          float v00 = __uint_as_float(((unsigned)(unsigned short)s00[q]) << 16);
          float v01 = __uint_as_float(((unsigned)(unsigned short)s01[q]) << 16);
          float v10 = __uint_as_float(((unsigned)(unsigned short)s10[q]) << 16);
          float v11 = __uint_as_float(((unsigned)(unsigned short)s11[q]) << 16);
          acc[q] += v00 * w00 + v01 * w01 + v10 * w10 + v11 * w11;
        }
      }
    }
    __hip_bfloat16 o[4] = {__float2bfloat16(acc[0] * 0.25f), __float2bfloat16(acc[1] * 0.25f),
                           __float2bfloat16(acc[2] * 0.25f), __float2bfloat16(acc[3] * 0.25f)};
    *(short4v*)&X[(size_t)n * K1P + (size_t)(py * 7 + px) * C_FEAT + c] = *(short4v*)o;
  }
}

// ------------------------------------------------------- bf16 MFMA GEMM (split-K)
// MODE 1: GEMM1 — 256x128 tile, 512 thr, 1-D grid 512, XCD slice-affinity swizzle
//         (all 32 blocks of K-slice z share lin%8 -> one XCD under round-robin;
//          slice A+B = 3.3 MB fits 4 MB XCD L2).
// MODE 2: GEMM2 — 128x128 tile, 256 thr, 1-D grid 256, slice z on XCD pair.
__device__ __forceinline__ void gld_lds16(const __hip_bfloat16* g, __hip_bfloat16* l) {
  __builtin_amdgcn_global_load_lds(
      (const __attribute__((address_space(1))) void*)g,
      (__attribute__((address_space(3))) void*)l, 16, 0, 0);
}

template <int MODE>
__global__ __launch_bounds__(MODE == 1 ? 512 : 256)
void k_mfma_gemm(const __hip_bfloat16* __restrict__ A,
                 const __hip_bfloat16* __restrict__ BT,
                 float* __restrict__ P, int K, int KC) {
  const int AM  = (MODE == 1) ? 256 : 128;
  const int TPB = AM * 2;
  __shared__ __align__(16) __hip_bfloat16 As[AM * 32];
  __shared__ __align__(16) __hip_bfloat16 Bs[128 * 32];
  int lin = blockIdx.x;
  int n0, m0, kz;
  if (MODE == 1) {
    int c = lin & 7, h = lin >> 8, q = (lin >> 3) & 31;
    kz = c + (h << 3);                 // 0..15
    n0 = (q & 7) * 128;                // 0..7
    m0 = (q >> 3) * 256;               // 0..3
  } else {
    int c = lin & 7;
    kz = c >> 1;                       // 0..3
    int q = (lin >> 3) + ((c & 1) << 5);
    n0 = (q & 7) * 128;
    m0 = (q >> 3) * 128;
  }
  int tid = threadIdx.x;
  int kbeg = kz * KC;
  int srow = tid >> 2;
  int scs  = tid & 3;
  int sg   = scs ^ (srow & 3);
  int scol = sg << 3;
  int wave = tid >> 6, lane = tid & 63;
  const int WMW = AM / 64;
  int wm = (wave % WMW) * 64, wn = (wave / WMW) * 64;
  int lm = lane & 15, quad = lane >> 4;
  int fco = ((quad ^ (lm & 3)) << 3);
  f32x4f acc[4][4] = {};
  for (int k0 = kbeg; k0 < kbeg + KC; k0 += 32) {
    __syncthreads();
#pragma unroll
    for (int r0 = 0; r0 < AM; r0 += TPB / 4)
      gld_lds16(A + (size_t)(m0 + r0 + srow) * K + k0 + scol, &As[(r0 + srow) * 32 + scs * 8]);
#pragma unroll
    for (int r0 = 0; r0 < 128; r0 += TPB / 4)
      gld_lds16(BT + (size_t)(n0 + r0 + srow) * K + k0 + scol, &Bs[(r0 + srow) * 32 + scs * 8]);
    __syncthreads();
    bf16x8f af[4], bf[4];
#pragma unroll
    for (int i = 0; i < 4; i++)
      af[i] = *(const bf16x8f*)&As[(wm + i * 16 + lm) * 32 + fco];
#pragma unroll
    for (int j = 0; j < 4; j++)
      bf[j] = *(const bf16x8f*)&Bs[(wn + j * 16 + lm) * 32 + fco];
#pragma unroll
    for (int i = 0; i < 4; i++)
#pragma unroll
      for (int j = 0; j < 4; j++)
        acc[i][j] = __builtin_amdgcn_mfma_f32_16x16x32_bf16(af[i], bf[j], acc[i][j], 0, 0, 0);
  }
  // C/D layout: col = lane&15, row = quad*4 + reg
#pragma unroll
  for (int i = 0; i < 4; i++)
#pragma unroll
    for (int j = 0; j < 4; j++) {
      float* base = P + ((size_t)kz << 20)
                      + (size_t)(m0 + wm + i * 16 + quad * 4) * HID
                      + (n0 + wn + j * 16 + lm);
#pragma unroll
      for (int r = 0; r < 4; r++) base[(size_t)r * HID] = acc[i][j][r];
    }
}

// reduce split-K partials + bias + relu -> bf16 (after GEMM1)
template <int Z>
__global__ __launch_bounds__(256) void k_reduce(const float* __restrict__ P,
                                                const float* __restrict__ bias,
                                                __hip_bfloat16* __restrict__ O) {
  int idx4 = blockIdx.x * 256 + threadIdx.x;
  int m = idx4 >> 8;
  int n4 = (idx4 & 255) << 2;
  float4 s = *(const float4*)(bias + n4);
#pragma unroll
  for (int z = 0; z < Z; z++) {
    float4 p = *(const float4*)(P + ((size_t)z << 20) + ((size_t)m << 10) + n4);
    s.x += p.x; s.y += p.y; s.z += p.z; s.w += p.w;
  }
  __hip_bfloat16 t[4] = {__float2bfloat16(fmaxf(s.x, 0.0f)), __float2bfloat16(fmaxf(s.y, 0.0f)),
                         __float2bfloat16(fmaxf(s.z, 0.0f)), __float2bfloat16(fmaxf(s.w, 0.0f))};
  *(short4v*)(O + ((size_t)m << 10) + n4) = *(short4v*)t;
}

// ---------------------- reduce GEMM2 partials + bias + relu + head, fused.
__global__ __launch_bounds__(256) void k_reduce_head(const float* __restrict__ P,
                                                     const float* __restrict__ bias,
                                                     const float* __restrict__ wc,
                                                     const float* __restrict__ bc,
                                                     const float* __restrict__ wr,
                                                     const float* __restrict__ br,
                                                     float* __restrict__ Y) {
  __shared__ float part[4][NHEAD];
  int m = blockIdx.x, tid = threadIdx.x;
  int n4 = tid << 2;
  float4 s = *(const float4*)(bias + n4);
#pragma unroll
  for (int z = 0; z < SPLITK2; z++) {
    float4 p = *(const float4*)(P + ((size_t)z << 20) + ((size_t)m << 10) + n4);
    s.x += p.x; s.y += p.y; s.z += p.z; s.w += p.w;
  }
  float hv4[4] = {fmaxf(s.x, 0.0f), fmaxf(s.y, 0.0f), fmaxf(s.z, 0.0f), fmaxf(s.w, 0.0f)};
  float a[NHEAD];
#pragma unroll
  for (int j = 0; j < NHEAD; j++) a[j] = 0.0f;
#pragma unroll
  for (int q = 0; q < 4; q++) {
    int kk = n4 + q;
    float hv = hv4[q];
    float2 wcv = *(const float2*)(wc + kk * 2);
    float4 w0 = *(const float4*)(wr + kk * 12);
    float4 w1 = *(const float4*)(wr + kk * 12 + 4);
    float4 w2 = *(const float4*)(wr + kk * 12 + 8);
    a[0] += hv * wcv.x;  a[1] += hv * wcv.y;
    a[2] += hv * w0.x;   a[3] += hv * w0.y;  a[4] += hv * w0.z;  a[5] += hv * w0.w;
    a[6] += hv * w1.x;   a[7] += hv * w1.y;  a[8] += hv * w1.z;  a[9] += hv * w1.w;
    a[10] += hv * w2.x;  a[11] += hv * w2.y; a[12] += hv * w2.z; a[13] += hv * w2.w;
  }
#pragma unroll
  for (int j = 0; j < NHEAD; j++)
#pragma unroll
    for (int off = 32; off > 0; off >>= 1) a[j] += __shfl_down(a[j], off);
  int wave = tid >> 6, lane = tid & 63;
  if (lane == 0)
#pragma unroll
    for (int j = 0; j < NHEAD; j++) part[wave][j] = a[j];
  __syncthreads();
  if (tid < NHEAD) {
    float v = part[0][tid] + part[1][tid] + part[2][tid] + part[3][tid];
    Y[(size_t)m * NHEAD + tid] = v + ((tid < 2) ? bc[tid] : br[tid - 2]);
  }
}

// ------------------------------------------------------------------- losses
__global__ __launch_bounds__(1024) void k_loss(const float* __restrict__ Y,
                                               const int* __restrict__ sel_labels,
                                               const float* __restrict__ T,
                                               float* __restrict__ out) {
  __shared__ float sc[1024];
  __shared__ float sr[1024];
  int n = threadIdx.x;
  float l0 = Y[(size_t)n * NHEAD + 0], l1 = Y[(size_t)n * NHEAD + 1];
  int lb = sel_labels[n];
  float mx = fmaxf(l0, l1);
  float lse = mx + logf(expf(l0 - mx) + expf(l1 - mx));
  float ce = lse - (lb ? l1 : l0);
  float reg = 0.0f;
  if (lb > 0) {
    const float beta = 1.0f / 9.0f;
    const float* pr = Y + (size_t)n * NHEAD + 2 + lb * 6;
    const float* t = T + (size_t)n * 6;
#pragma unroll
    for (int j = 0; j < 6; j++) {
      float d = fabsf(pr[j] - t[j]);
      reg += (d < beta) ? (0.5f * d * d / beta) : (d - 0.5f * beta);
    }
  }
  sc[n] = ce; sr[n] = reg;
  __syncthreads();
  for (int s = 512; s > 0; s >>= 1) {
    if (n < s) { sc[n] += sc[n + s]; sr[n] += sr[n + s]; }
    __syncthreads();
  }
  if (n == 0) {
    out[0] = sc[0] * (1.0f / 1024.0f);
    out[1] = sr[0] * (1.0f / 1024.0f);
  }
}

// ------------------------------------------------------------------ launch
extern "C" void kernel_launch(void* const* d_in, const int* in_sizes, int n_in,
                              void* d_out, int out_size, void* d_ws, size_t ws_size,
                              hipStream_t stream) {
  const float* features  = (const float*)d_in[0];
  const float* proposals = (const float*)d_in[1];
  const float* gt_boxes  = (const float*)d_in[2];
  const int*   gt_labels = (const int*)d_in[3];
  const float* gt_ell    = (const float*)d_in[4];
  const float* w1 = (const float*)d_in[5];
  const float* b1 = (const float*)d_in[6];
  const float* w2 = (const float*)d_in[7];
  const float* b2 = (const float*)d_in[8];
  const float* wc = (const float*)d_in[9];
  const float* bc = (const float*)d_in[10];
  const float* wr = (const float*)d_in[11];
  const float* br = (const float*)d_in[12];
  float* out = (float*)d_out;

  char* ws = (char*)d_ws;
  size_t off = 0;
  auto take = [&](size_t bytes) -> void* {
    void* p = ws + off;
    off = (off + bytes + 255) & ~(size_t)255;
    return p;
  };
  // region0 hosts featT (bf16, 16.7 MB, dead after roialign) then P (16x4 MiB partials)
  float* P = (float*)take((size_t)SPLITK1 * HID * HID * 4);            // 67.1 MB
  __hip_bfloat16* featT = (__hip_bfloat16*)P;                          // alias
  __hip_bfloat16* Xb  = (__hip_bfloat16*)take((size_t)NSEL * K1P * 2); // 26.2 MB
  float* Y   = (float*)Xb;                                             // alias (post-GEMM1)
  __hip_bfloat16* W1T = (__hip_bfloat16*)take((size_t)HID * K1P * 2);  // 26.2 MB
  __hip_bfloat16* W2T = (__hip_bfloat16*)take((size_t)HID * HID * 2);  // 2.1 MB
  __hip_bfloat16* H1b = (__hip_bfloat16*)take((size_t)NSEL * HID * 2); // 2.1 MB
  int*   matches   = (int*)take((size_t)B_IMG * NPROPS * 4);
  int*   plab      = (int*)take((size_t)B_IMG * NPROPS * 4);
  float* prio      = (float*)take((size_t)B_IMG * NPROPS * 4);
  float* sel_boxes = (float*)take((size_t)NSEL * 4 * 4);
  int*   sel_lab   = (int*)take((size_t)NSEL * 4);
  float* targets   = (float*)take((size_t)NSEL * 6 * 4);

  k_sample<<<B_IMG, 256, 0, stream>>>(proposals, gt_boxes, gt_labels, prio, plab, matches);
  k_pad<<<dim3(256, 2), 256, 0, stream>>>(Xb, W1T);
  k_transpose<<<dim3(HWF / 64, C_FEAT / 64, B_IMG), 256, 0, stream>>>(features, featT);
  k_castT<1><<<dim3(C_FEAT / 64, HID / 64, 49), 256, 0, stream>>>(w1, W1T, K1P);
  k_castT<0><<<dim3(HID / 64, HID / 64, 1), 256, 0, stream>>>(w2, W2T, HID);
  k_select<<<dim3(NPROPS / 4, B_IMG), 256, 0, stream>>>(prio, proposals, gt_boxes,
                                                        matches, plab, gt_ell,
                                                        sel_boxes, sel_lab, targets);
  k_roialign<<<dim3(NSEL, POOL), 256, 0, stream>>>(featT, sel_boxes, Xb);

  // GEMM1: Xb(1024 x 12800) @ W1T^T, 256x128 tile, split-K=16 (KC=800), 512 blocks (2/CU)
  k_mfma_gemm<1><<<512, 512, 0, stream>>>(Xb, W1T, P, K1P, K1P / SPLITK1);
  k_reduce<SPLITK1><<<1024, 256, 0, stream>>>(P, b1, H1b);
  // GEMM2: H1b(1024x1024) @ W2T^T, 128x128 tile, split-K=4 -> fused reduce+relu+head
  k_mfma_gemm<2><<<256, 256, 0, stream>>>(H1b, W2T, P, HID, HID / SPLITK2);
  k_reduce_head<<<1024, 256, 0, stream>>>(P, b2, wc, bc, wr, br, Y);

  k_loss<<<1, 1024, 0, stream>>>(Y, sel_lab, targets, out);
}

// Round 9
// 239.204 us; speedup vs baseline: 1.5641x; 1.2012x over previous
//
#include <hip/hip_runtime.h>
#include <hip/hip_bf16.h>
#include <math.h>

#define B_IMG   2
#define N_PROP  2000
#define N_GT    16
#define NPROPS  2016        // N_PROP + N_GT
#define C_FEAT  256
#define H_FEAT  128
#define W_FEAT  128
#define HWF     (H_FEAT*W_FEAT)
#define POOL    7
#define BPI     512
#define NPOSMAX 128
#define NSEL    (B_IMG*BPI)     // 1024
#define K1      (C_FEAT*POOL*POOL)  // 12544
#define K1P     12800           // K1 padded to 16*800
#define HID     1024
#define NHEAD   14
#define SPLITK1 16              // KC = 800
#define SPLITK2 8               // KC = 128

typedef short bf16x8f __attribute__((ext_vector_type(8)));
typedef float f32x4f  __attribute__((ext_vector_type(4)));
typedef short short4v __attribute__((ext_vector_type(4)));

// ---------------------------------------------------------------- threefry
__device__ __forceinline__ void threefry2x32(unsigned k0, unsigned k1,
                                             unsigned& x0, unsigned& x1) {
  unsigned ks[3] = {k0, k1, k0 ^ k1 ^ 0x1BD11BDAu};
  const int R0[4] = {13, 15, 26, 6};
  const int R1[4] = {17, 29, 16, 24};
  x0 += ks[0]; x1 += ks[1];
#pragma unroll
  for (int g = 0; g < 5; g++) {
    const int* rot = (g & 1) ? R1 : R0;
#pragma unroll
    for (int r = 0; r < 4; r++) {
      x0 += x1;
      x1 = (x1 << rot[r]) | (x1 >> (32 - rot[r]));
      x1 ^= x0;
    }
    x0 += ks[(g + 1) % 3];
    x1 += ks[(g + 2) % 3] + (unsigned)(g + 1);
  }
}

// ---------------- mega-prologue: sample(2) | transpose(2048) | castT1(3136)
//                  | castT0(256) | pad(512)  — blockIdx-range dispatch
#define PRE_SAMPLE   2
#define PRE_TRANS    (PRE_SAMPLE + 2048)
#define PRE_CAST1    (PRE_TRANS + 3136)
#define PRE_CAST0    (PRE_CAST1 + 256)
#define PRE_TOTAL    (PRE_CAST0 + 512)

__global__ __launch_bounds__(256) void k_pre(const float* __restrict__ proposals,
                                             const float* __restrict__ gt_boxes,
                                             const int* __restrict__ gt_labels,
                                             const float* __restrict__ features,
                                             const float* __restrict__ w1,
                                             const float* __restrict__ w2,
                                             float* __restrict__ prio,
                                             int* __restrict__ plab,
                                             int* __restrict__ matches,
                                             __hip_bfloat16* __restrict__ featT,
                                             __hip_bfloat16* __restrict__ W1T,
                                             __hip_bfloat16* __restrict__ W2T,
                                             __hip_bfloat16* __restrict__ Xb) {
  __shared__ __align__(16) char smem[20800];
  int bid = blockIdx.x;
  int tid = threadIdx.x;
  if (bid < PRE_SAMPLE) {
    // ---------------- sample: rand + IoU match + positive-rank priorities
    float* rs    = (float*)smem;              // 2016
    float* pos_r = (float*)(smem + 8064);     // 2016
    short* pos_i = (short*)(smem + 16128);    // 2016
    float* gtb   = (float*)(smem + 20160);    // 64
    int*   gtl   = (int*)(smem + 20416);      // 16
    int*   cnt   = (int*)(smem + 20480);
    int b = bid;
    int base = b * NPROPS;
    if (tid == 0) *cnt = 0;
    if (tid < N_GT * 4) gtb[tid] = gt_boxes[b * N_GT * 4 + tid];
    if (tid < N_GT) gtl[tid] = gt_labels[b * N_GT + tid];
    __syncthreads();
    for (int i = tid; i < NPROPS; i += 256) {
      unsigned x0 = 0u, x1 = (unsigned)(base + i);
      threefry2x32(0u, 42u, x0, x1);
      unsigned bits = x0 ^ x1;
      float r = __uint_as_float((bits >> 9) | 0x3F800000u) - 1.0f;
      rs[i] = r;
      float p0, p1, p2, p3;
      if (i < N_PROP) {
        const float4 v = *(const float4*)(proposals + ((size_t)b * N_PROP + i) * 4);
        p0 = v.x; p1 = v.y; p2 = v.z; p3 = v.w;
      } else {
        const float* g = &gtb[(i - N_PROP) * 4];
        p0 = g[0]; p1 = g[1]; p2 = g[2]; p3 = g[3];
      }
      float a2 = (p2 - p0) * (p3 - p1);
      float best = -1.0f; int bg = 0;
#pragma unroll
      for (int g = 0; g < N_GT; g++) {
        float g0 = gtb[g*4], g1 = gtb[g*4+1], g2 = gtb[g*4+2], g3 = gtb[g*4+3];
        float a1 = (g2 - g0) * (g3 - g1);
        float wx = fmaxf(fminf(g2, p2) - fmaxf(g0, p0), 0.0f);
        float wy = fmaxf(fminf(g3, p3) - fmaxf(g1, p1), 0.0f);
        float inter = wx * wy;
        float iou = inter / (a1 + a2 - inter);
        if (iou > best) { best = iou; bg = g; }
      }
      matches[base + i] = bg;
      int lab = (best < 0.5f) ? 0 : gtl[bg];
      plab[base + i] = lab;
      if (lab > 0) {
        int s = atomicAdd(cnt, 1);
        pos_i[s] = (short)i; pos_r[s] = r;
      }
    }
    __syncthreads();
    int P = *cnt;
    for (int s = tid; s < P; s += 256) {
      int i = pos_i[s]; float ri = pos_r[s];
      int ch = 0;
      for (int j = 0; j < P; j++) {
        float rj = pos_r[j]; int ij = pos_i[j];
        ch += (rj > ri || (rj == ri && ij < i)) ? 1 : 0;
      }
      rs[i] = (ch < NPOSMAX) ? (ri + 2.0f) : -1000000000.0f;
    }
    __syncthreads();
    for (int i = tid; i < NPROPS; i += 256) prio[base + i] = rs[i];
  } else if (bid < PRE_TRANS) {
    // ---------------- NCHW -> NHWC bf16, 64x64 tiles
    float (*tile)[65] = (float(*)[65])smem;
    int t = bid - PRE_SAMPLE;
    int b = t >> 10;
    int rem = t & 1023;
    int c0 = (rem >> 8) * 64;
    int s0 = (rem & 255) * 64;
    const float* src = features + (size_t)b * C_FEAT * HWF;
    __hip_bfloat16* dst = featT + (size_t)b * HWF * C_FEAT;
    int hw4 = (tid & 15) * 4, cr = tid >> 4;
#pragma unroll
    for (int p = 0; p < 4; p++) {
      int c = cr + p * 16;
      float4 v = *(const float4*)(src + (size_t)(c0 + c) * HWF + s0 + hw4);
      tile[hw4 + 0][c] = v.x; tile[hw4 + 1][c] = v.y;
      tile[hw4 + 2][c] = v.z; tile[hw4 + 3][c] = v.w;
    }
    __syncthreads();
    int c4 = (tid & 15) * 4, hr = tid >> 4;
#pragma unroll
    for (int p = 0; p < 4; p++) {
      int hw = hr + p * 16;
      __hip_bfloat16 o[4] = {__float2bfloat16(tile[hw][c4]), __float2bfloat16(tile[hw][c4+1]),
                             __float2bfloat16(tile[hw][c4+2]), __float2bfloat16(tile[hw][c4+3])};
      *(short4v*)(dst + (size_t)(s0 + hw) * C_FEAT + c0 + c4) = *(short4v*)o;
    }
  } else if (bid < PRE_CAST1) {
    // ---------------- w1 cast: fp32 [c*49+p][N] -> bf16 [N][p*256+c]
    float (*tile)[65] = (float(*)[65])smem;
    int t = bid - PRE_TRANS;
    int p = t >> 6;
    int rem = t & 63;
    int c0 = (rem & 3) * 64;
    int n0 = (rem >> 2) * 64;
    int tx = tid & 63, ty = tid >> 6;
#pragma unroll
    for (int i = ty; i < 64; i += 4)
      tile[i][tx] = w1[(size_t)((c0 + i) * 49 + p) * HID + n0 + tx];
    __syncthreads();
#pragma unroll
    for (int i = ty; i < 64; i += 4)
      W1T[(size_t)(n0 + i) * K1P + p * 256 + c0 + tx] = __float2bfloat16(tile[tx][i]);
  } else if (bid < PRE_CAST0) {
    // ---------------- w2 cast: fp32 [K][N] -> bf16 [N][K]
    float (*tile)[65] = (float(*)[65])smem;
    int t = bid - PRE_CAST1;
    int c0 = (t & 15) * 64;
    int n0 = (t >> 4) * 64;
    int tx = tid & 63, ty = tid >> 6;
#pragma unroll
    for (int i = ty; i < 64; i += 4)
      tile[i][tx] = w2[(size_t)(c0 + i) * HID + n0 + tx];
    __syncthreads();
#pragma unroll
    for (int i = ty; i < 64; i += 4)
      W2T[(size_t)(n0 + i) * HID + c0 + tx] = __float2bfloat16(tile[tx][i]);
  } else {
    // ---------------- zero K-pad cols K1..K1P of Xb / W1T
    int t = bid - PRE_CAST0;        // 0..511
    __hip_bfloat16* buf = (t >> 8) ? W1T : Xb;
    int tt = (t & 255) * 256 + tid;
    int row = tt >> 6;
    int col4 = (tt & 63) << 2;
    short4v z = {0, 0, 0, 0};
    *(short4v*)(buf + (size_t)row * K1P + K1 + col4) = z;
  }
}

// ------------------------------------------------- select + gather + encode
__global__ __launch_bounds__(256) void k_select(const float* __restrict__ prio,
    const float* __restrict__ proposals, const float* __restrict__ gt_boxes,
    const int* __restrict__ matches, const int* __restrict__ plab,
    const float* __restrict__ gt_ell,
    float* __restrict__ sel_boxes, int* __restrict__ sel_labels,
    float* __restrict__ targets) {
  int tid = threadIdx.x;
  int wave = tid >> 6, lane = tid & 63;
  int b = blockIdx.y;
  int base = b * NPROPS;
  int i = blockIdx.x * 4 + wave;
  float pi = prio[base + i];
  int rank = 0;
  for (int j = lane; j < NPROPS; j += 64) {
    float pj = prio[base + j];
    rank += (pj > pi || (pj == pi && j < i)) ? 1 : 0;
  }
#pragma unroll
  for (int off = 32; off > 0; off >>= 1) rank += __shfl_down(rank, off);
  if (lane != 0 || rank >= BPI) return;
  int slot = b * BPI + rank;
  float p0, p1, p2, p3;
  if (i < N_PROP) {
    const float* p = proposals + ((size_t)b * N_PROP + i) * 4;
    p0 = p[0]; p1 = p[1]; p2 = p[2]; p3 = p[3];
  } else {
    const float* p = gt_boxes + ((size_t)b * N_GT + (i - N_PROP)) * 4;
    p0 = p[0]; p1 = p[1]; p2 = p[2]; p3 = p[3];
  }
  sel_boxes[slot * 4 + 0] = p0;
  sel_boxes[slot * 4 + 1] = p1;
  sel_boxes[slot * 4 + 2] = p2;
  sel_boxes[slot * 4 + 3] = p3;
  int lb = plab[base + i];
  sel_labels[slot] = lb;
  int m = matches[base + i];
  const float* e = gt_ell + ((size_t)b * N_GT + m) * 5;
  float ea = e[0], eb = e[1], ex = e[2], ey = e[3], eth = e[4];
  float w = fmaxf(p2 - p0, 1.0f), h = fmaxf(p3 - p1, 1.0f);
  float cx = 0.5f * (p0 + p2), cy = 0.5f * (p1 + p3);
  float* t = targets + (size_t)slot * 6;
  t[0] = (ex - cx) / w;
  t[1] = (ey - cy) / h;
  t[2] = logf(fmaxf(2.0f * ea, 0.001f) / w);
  t[3] = logf(fmaxf(2.0f * eb, 0.001f) / h);
  t[4] = sinf(2.0f * eth);
  t[5] = cosf(2.0f * eth);
}

// ---------------------------------------------------------------- roi align (bf16 feat)
__global__ __launch_bounds__(256) void k_roialign(const __hip_bfloat16* __restrict__ featT,
                                                  const float* __restrict__ sel_boxes,
                                                  __hip_bfloat16* __restrict__ X) {
  int n = blockIdx.x;
  int py = blockIdx.y;
  int t = threadIdx.x;
  int lane = t & 63, sub = t >> 6;
  int c = lane << 2;
  int b = n >> 9;
  const float* bx = sel_boxes + (size_t)n * 4;
  float x1 = bx[0] * 0.125f, y1 = bx[1] * 0.125f;
  float x2 = bx[2] * 0.125f, y2 = bx[3] * 0.125f;
  float bw = fmaxf(x2 - x1, 1.0f) / 7.0f;
  float bh = fmaxf(y2 - y1, 1.0f) / 7.0f;
  const __hip_bfloat16* base = featT + (size_t)b * HWF * C_FEAT;
  int y0A[2]; float lyA[2];
#pragma unroll
  for (int sy = 0; sy < 2; sy++) {
    float off = ((float)(py * 2 + sy) + 0.5f) * 0.5f;
    float ys = fminf(fmaxf(y1 + off * bh, 0.0f), 127.0f);
    int y0 = (int)fminf(fmaxf(floorf(ys), 0.0f), 126.0f);
    y0A[sy] = y0; lyA[sy] = ys - (float)y0;
  }
#pragma unroll
  for (int pass = 0; pass < 2; pass++) {
    int px = sub + (pass << 2);
    if (px >= 7) break;
    float acc[4] = {0.0f, 0.0f, 0.0f, 0.0f};
#pragma unroll
    for (int sx = 0; sx < 2; sx++) {
      float off = ((float)(px * 2 + sx) + 0.5f) * 0.5f;
      float xs = fminf(fmaxf(x1 + off * bw, 0.0f), 127.0f);
      int x0 = (int)fminf(fmaxf(floorf(xs), 0.0f), 126.0f);
      float lx = xs - (float)x0;
#pragma unroll
      for (int sy = 0; sy < 2; sy++) {
        int y0 = y0A[sy]; float ly = lyA[sy];
        const __hip_bfloat16* p = base + ((size_t)(y0 * W_FEAT + x0)) * C_FEAT + c;
        short4v s00 = *(const short4v*)p;
        short4v s01 = *(const short4v*)(p + C_FEAT);
        short4v s10 = *(const short4v*)(p + W_FEAT * C_FEAT);
        short4v s11 = *(const short4v*)(p + W_FEAT * C_FEAT + C_FEAT);
        float w00 = (1.0f - ly) * (1.0f - lx), w01 = (1.0f - ly) * lx;
        float w10 = ly * (1.0f - lx), w11 = ly * lx;
#pragma unroll
        for (int q = 0; q < 4; q++) {
          float v00 = __uint_as_float(((unsigned)(unsigned short)s00[q]) << 16);
          float v01 = __uint_as_float(((unsigned)(unsigned short)s01[q]) << 16);
          float v10 = __uint_as_float(((unsigned)(unsigned short)s10[q]) << 16);
          float v11 = __uint_as_float(((unsigned)(unsigned short)s11[q]) << 16);
          acc[q] += v00 * w00 + v01 * w01 + v10 * w10 + v11 * w11;
        }
      }
    }
    __hip_bfloat16 o[4] = {__float2bfloat16(acc[0] * 0.25f), __float2bfloat16(acc[1] * 0.25f),
                           __float2bfloat16(acc[2] * 0.25f), __float2bfloat16(acc[3] * 0.25f)};
    *(short4v*)&X[(size_t)n * K1P + (size_t)(py * 7 + px) * C_FEAT + c] = *(short4v*)o;
  }
}

// ------------------------------------------------------- bf16 MFMA GEMM (split-K)
// Partials stored PACKED bf16: slab(kz,1M elems) + tile + wave*4096 + frag*256 + lane*4+r
__device__ __forceinline__ void gld_lds16(const __hip_bfloat16* g, __hip_bfloat16* l) {
  __builtin_amdgcn_global_load_lds(
      (const __attribute__((address_space(1))) void*)g,
      (__attribute__((address_space(3))) void*)l, 16, 0, 0);
}

template <int MODE>
__global__ __launch_bounds__(MODE == 1 ? 512 : 256)
void k_mfma_gemm(const __hip_bfloat16* __restrict__ A,
                 const __hip_bfloat16* __restrict__ BT,
                 __hip_bfloat16* __restrict__ Pb, int K, int KC) {
  const int AM  = (MODE == 1) ? 256 : 128;
  const int TPB = AM * 2;
  __shared__ __align__(16) __hip_bfloat16 As[AM * 32];
  __shared__ __align__(16) __hip_bfloat16 Bs[128 * 32];
  int lin = blockIdx.x;
  int n0, m0, kz;
  if (MODE == 1) {
    int c = lin & 7, h = lin >> 8, q = (lin >> 3) & 31;
    kz = c + (h << 3);
    n0 = (q & 7) * 128;
    m0 = (q >> 3) * 256;
  } else {
    kz = lin & 7;
    int q = lin >> 3;
    n0 = (q & 7) * 128;
    m0 = (q >> 3) * 128;
  }
  int tid = threadIdx.x;
  int kbeg = kz * KC;
  int srow = tid >> 2;
  int scs  = tid & 3;
  int sg   = scs ^ (srow & 3);
  int scol = sg << 3;
  int wave = tid >> 6, lane = tid & 63;
  const int WMW = AM / 64;
  int wm = (wave % WMW) * 64, wn = (wave / WMW) * 64;
  int lm = lane & 15, quad = lane >> 4;
  int fco = ((quad ^ (lm & 3)) << 3);
  f32x4f acc[4][4] = {};
  for (int k0 = kbeg; k0 < kbeg + KC; k0 += 32) {
    __syncthreads();
#pragma unroll
    for (int r0 = 0; r0 < AM; r0 += TPB / 4)
      gld_lds16(A + (size_t)(m0 + r0 + srow) * K + k0 + scol, &As[(r0 + srow) * 32 + scs * 8]);
#pragma unroll
    for (int r0 = 0; r0 < 128; r0 += TPB / 4)
      gld_lds16(BT + (size_t)(n0 + r0 + srow) * K + k0 + scol, &Bs[(r0 + srow) * 32 + scs * 8]);
    __syncthreads();
    bf16x8f af[4], bf[4];
#pragma unroll
    for (int i = 0; i < 4; i++)
      af[i] = *(const bf16x8f*)&As[(wm + i * 16 + lm) * 32 + fco];
#pragma unroll
    for (int j = 0; j < 4; j++)
      bf[j] = *(const bf16x8f*)&Bs[(wn + j * 16 + lm) * 32 + fco];
#pragma unroll
    for (int i = 0; i < 4; i++)
#pragma unroll
      for (int j = 0; j < 4; j++)
        acc[i][j] = __builtin_amdgcn_mfma_f32_16x16x32_bf16(af[i], bf[j], acc[i][j], 0, 0, 0);
  }
  int tileoff = (MODE == 1) ? (((m0 >> 8) * 8 + (n0 >> 7)) * 32768)
                            : (((m0 >> 7) * 8 + (n0 >> 7)) * 16384);
  __hip_bfloat16* dst = Pb + ((size_t)kz << 20) + tileoff + wave * 4096 + lane * 4;
#pragma unroll
  for (int i = 0; i < 4; i++)
#pragma unroll
    for (int j = 0; j < 4; j++) {
      __hip_bfloat16 o[4] = {__float2bfloat16(acc[i][j][0]), __float2bfloat16(acc[i][j][1]),
                             __float2bfloat16(acc[i][j][2]), __float2bfloat16(acc[i][j][3])};
      *(short4v*)(dst + (i * 4 + j) * 256) = *(short4v*)o;
    }
}

// ---------------- reduce GEMM1 packed partials + bias + relu -> H1b (bf16)
// grid 1024: bx>>2 = m4 (4 rows), bx&3 = n-group; thread = n within group.
__global__ __launch_bounds__(256) void k_reduce16(const __hip_bfloat16* __restrict__ Pb,
                                                  const float* __restrict__ bias,
                                                  __hip_bfloat16* __restrict__ O) {
  int m4 = blockIdx.x >> 2;
  int n  = (blockIdx.x & 3) * 256 + threadIdx.x;
  int m0i = m4 >> 6, wavem = (m4 >> 4) & 3, i = (m4 >> 2) & 3, quad = m4 & 3;
  int n0i = n >> 7, wn = (n >> 6) & 1, j = (n >> 4) & 3, lm = n & 15;
  int wave = wavem + wn * 4;
  int elem = (m0i * 8 + n0i) * 32768 + wave * 4096 + (i * 4 + j) * 256 + (quad * 16 + lm) * 4;
  float s0 = 0.0f, s1 = 0.0f, s2 = 0.0f, s3 = 0.0f;
#pragma unroll
  for (int z = 0; z < SPLITK1; z++) {
    short4v v = *(const short4v*)(Pb + ((size_t)z << 20) + elem);
    s0 += __uint_as_float(((unsigned)(unsigned short)v[0]) << 16);
    s1 += __uint_as_float(((unsigned)(unsigned short)v[1]) << 16);
    s2 += __uint_as_float(((unsigned)(unsigned short)v[2]) << 16);
    s3 += __uint_as_float(((unsigned)(unsigned short)v[3]) << 16);
  }
  float bv = bias[n];
  int m = m4 * 4;
  O[(size_t)(m + 0) * HID + n] = __float2bfloat16(fmaxf(s0 + bv, 0.0f));
  O[(size_t)(m + 1) * HID + n] = __float2bfloat16(fmaxf(s1 + bv, 0.0f));
  O[(size_t)(m + 2) * HID + n] = __float2bfloat16(fmaxf(s2 + bv, 0.0f));
  O[(size_t)(m + 3) * HID + n] = __float2bfloat16(fmaxf(s3 + bv, 0.0f));
}

// ---------------- reduce GEMM2 packed partials + bias + relu + head, fused.
__global__ __launch_bounds__(256) void k_reduce_head(const __hip_bfloat16* __restrict__ Pb,
                                                     const float* __restrict__ bias,
                                                     const float* __restrict__ wc,
                                                     const float* __restrict__ bc,
                                                     const float* __restrict__ wr,
                                                     const float* __restrict__ br,
                                                     float* __restrict__ Y) {
  __shared__ float part[4][NHEAD];
  int m = blockIdx.x, tid = threadIdx.x;
  int m0i = m >> 7, wavem = (m >> 6) & 1, fi = (m >> 4) & 3, quad = (m >> 2) & 3, r = m & 3;
  float a[NHEAD];
#pragma unroll
  for (int j = 0; j < NHEAD; j++) a[j] = 0.0f;
#pragma unroll
  for (int nn = 0; nn < 4; nn++) {
    int n = nn * 256 + tid;
    int n0i = n >> 7, wn = (n >> 6) & 1, fj = (n >> 4) & 3, lm = n & 15;
    int wave = wavem + wn * 2;
    int elem = (m0i * 8 + n0i) * 16384 + wave * 4096 + (fi * 4 + fj) * 256
             + (quad * 16 + lm) * 4 + r;
    float s = 0.0f;
#pragma unroll
    for (int z = 0; z < SPLITK2; z++)
      s += __uint_as_float(((unsigned)*(const unsigned short*)(Pb + ((size_t)z << 20) + elem)) << 16);
    float hv = fmaxf(s + bias[n], 0.0f);
    float2 wcv = *(const float2*)(wc + n * 2);
    float4 w0 = *(const float4*)(wr + n * 12);
    float4 w1 = *(const float4*)(wr + n * 12 + 4);
    float4 w2 = *(const float4*)(wr + n * 12 + 8);
    a[0] += hv * wcv.x;  a[1] += hv * wcv.y;
    a[2] += hv * w0.x;   a[3] += hv * w0.y;  a[4] += hv * w0.z;  a[5] += hv * w0.w;
    a[6] += hv * w1.x;   a[7] += hv * w1.y;  a[8] += hv * w1.z;  a[9] += hv * w1.w;
    a[10] += hv * w2.x;  a[11] += hv * w2.y; a[12] += hv * w2.z; a[13] += hv * w2.w;
  }
#pragma unroll
  for (int j = 0; j < NHEAD; j++)
#pragma unroll
    for (int off = 32; off > 0; off >>= 1) a[j] += __shfl_down(a[j], off);
  int wave = tid >> 6, lane = tid & 63;
  if (lane == 0)
#pragma unroll
    for (int j = 0; j < NHEAD; j++) part[wave][j] = a[j];
  __syncthreads();
  if (tid < NHEAD) {
    float v = part[0][tid] + part[1][tid] + part[2][tid] + part[3][tid];
    Y[(size_t)m * NHEAD + tid] = v + ((tid < 2) ? bc[tid] : br[tid - 2]);
  }
}

// ------------------------------------------------------------------- losses
__global__ __launch_bounds__(1024) void k_loss(const float* __restrict__ Y,
                                               const int* __restrict__ sel_labels,
                                               const float* __restrict__ T,
                                               float* __restrict__ out) {
  __shared__ float sc[1024];
  __shared__ float sr[1024];
  int n = threadIdx.x;
  float l0 = Y[(size_t)n * NHEAD + 0], l1 = Y[(size_t)n * NHEAD + 1];
  int lb = sel_labels[n];
  float mx = fmaxf(l0, l1);
  float lse = mx + logf(expf(l0 - mx) + expf(l1 - mx));
  float ce = lse - (lb ? l1 : l0);
  float reg = 0.0f;
  if (lb > 0) {
    const float beta = 1.0f / 9.0f;
    const float* pr = Y + (size_t)n * NHEAD + 2 + lb * 6;
    const float* t = T + (size_t)n * 6;
#pragma unroll
    for (int j = 0; j < 6; j++) {
      float d = fabsf(pr[j] - t[j]);
      reg += (d < beta) ? (0.5f * d * d / beta) : (d - 0.5f * beta);
    }
  }
  sc[n] = ce; sr[n] = reg;
  __syncthreads();
  for (int s = 512; s > 0; s >>= 1) {
    if (n < s) { sc[n] += sc[n + s]; sr[n] += sr[n + s]; }
    __syncthreads();
  }
  if (n == 0) {
    out[0] = sc[0] * (1.0f / 1024.0f);
    out[1] = sr[0] * (1.0f / 1024.0f);
  }
}

// ------------------------------------------------------------------ launch
extern "C" void kernel_launch(void* const* d_in, const int* in_sizes, int n_in,
                              void* d_out, int out_size, void* d_ws, size_t ws_size,
                              hipStream_t stream) {
  const float* features  = (const float*)d_in[0];
  const float* proposals = (const float*)d_in[1];
  const float* gt_boxes  = (const float*)d_in[2];
  const int*   gt_labels = (const int*)d_in[3];
  const float* gt_ell    = (const float*)d_in[4];
  const float* w1 = (const float*)d_in[5];
  const float* b1 = (const float*)d_in[6];
  const float* w2 = (const float*)d_in[7];
  const float* b2 = (const float*)d_in[8];
  const float* wc = (const float*)d_in[9];
  const float* bc = (const float*)d_in[10];
  const float* wr = (const float*)d_in[11];
  const float* br = (const float*)d_in[12];
  float* out = (float*)d_out;

  char* ws = (char*)d_ws;
  size_t off = 0;
  auto take = [&](size_t bytes) -> void* {
    void* p = ws + off;
    off = (off + bytes + 255) & ~(size_t)255;
    return p;
  };
  // Pb (packed bf16 partials, 16 x 2 MiB) hosts featT (16.7 MB) pre-GEMM
  __hip_bfloat16* Pb = (__hip_bfloat16*)take((size_t)SPLITK1 * (1 << 20) * 2); // 33.5 MB
  __hip_bfloat16* featT = Pb;                                                  // alias
  __hip_bfloat16* Xb  = (__hip_bfloat16*)take((size_t)NSEL * K1P * 2);         // 26.2 MB
  float* Y = (float*)Xb;                                                       // alias (post-GEMM1)
  __hip_bfloat16* W1T = (__hip_bfloat16*)take((size_t)HID * K1P * 2);          // 26.2 MB
  __hip_bfloat16* W2T = (__hip_bfloat16*)take((size_t)HID * HID * 2);          // 2.1 MB
  __hip_bfloat16* H1b = (__hip_bfloat16*)take((size_t)NSEL * HID * 2);         // 2.1 MB
  int*   matches   = (int*)take((size_t)B_IMG * NPROPS * 4);
  int*   plab      = (int*)take((size_t)B_IMG * NPROPS * 4);
  float* prio      = (float*)take((size_t)B_IMG * NPROPS * 4);
  float* sel_boxes = (float*)take((size_t)NSEL * 4 * 4);
  int*   sel_lab   = (int*)take((size_t)NSEL * 4);
  float* targets   = (float*)take((size_t)NSEL * 6 * 4);

  k_pre<<<PRE_TOTAL, 256, 0, stream>>>(proposals, gt_boxes, gt_labels, features,
                                       w1, w2, prio, plab, matches,
                                       featT, W1T, W2T, Xb);
  k_select<<<dim3(NPROPS / 4, B_IMG), 256, 0, stream>>>(prio, proposals, gt_boxes,
                                                        matches, plab, gt_ell,
                                                        sel_boxes, sel_lab, targets);
  k_roialign<<<dim3(NSEL, POOL), 256, 0, stream>>>(featT, sel_boxes, Xb);

  // GEMM1: 256x128 tile, split-K=16 (KC=800), 512 blocks, packed bf16 partials
  k_mfma_gemm<1><<<512, 512, 0, stream>>>(Xb, W1T, Pb, K1P, K1P / SPLITK1);
  k_reduce16<<<1024, 256, 0, stream>>>(Pb, b1, H1b);
  // GEMM2: 128x128 tile, split-K=8 (KC=128), 512 blocks -> fused reduce+relu+head
  k_mfma_gemm<2><<<512, 256, 0, stream>>>(H1b, W2T, Pb, HID, HID / SPLITK2);
  k_reduce_head<<<1024, 256, 0, stream>>>(Pb, b2, wc, bc, wr, br, Y);

  k_loss<<<1, 1024, 0, stream>>>(Y, sel_lab, targets, out);
}

// Round 10
// 238.767 us; speedup vs baseline: 1.5669x; 1.0018x over previous
//
#include <hip/hip_runtime.h>
#include <hip/hip_bf16.h>
#include <math.h>

#define B_IMG   2
#define N_PROP  2000
#define N_GT    16
#define NPROPS  2016        // N_PROP + N_GT
#define C_FEAT  256
#define H_FEAT  128
#define W_FEAT  128
#define HWF     (H_FEAT*W_FEAT)
#define POOL    7
#define BPI     512
#define NPOSMAX 128
#define NSEL    (B_IMG*BPI)     // 1024
#define K1      (C_FEAT*POOL*POOL)  // 12544
#define K1P     12800           // K1 padded to 16*800
#define HID     1024
#define NHEAD   14
#define SPLITK1 16              // KC = 800
#define SPLITK2 8               // KC = 128

typedef short bf16x8f __attribute__((ext_vector_type(8)));
typedef float f32x4f  __attribute__((ext_vector_type(4)));
typedef short short4v __attribute__((ext_vector_type(4)));

// ---------------------------------------------------------------- threefry
__device__ __forceinline__ void threefry2x32(unsigned k0, unsigned k1,
                                             unsigned& x0, unsigned& x1) {
  unsigned ks[3] = {k0, k1, k0 ^ k1 ^ 0x1BD11BDAu};
  const int R0[4] = {13, 15, 26, 6};
  const int R1[4] = {17, 29, 16, 24};
  x0 += ks[0]; x1 += ks[1];
#pragma unroll
  for (int g = 0; g < 5; g++) {
    const int* rot = (g & 1) ? R1 : R0;
#pragma unroll
    for (int r = 0; r < 4; r++) {
      x0 += x1;
      x1 = (x1 << rot[r]) | (x1 >> (32 - rot[r]));
      x1 ^= x0;
    }
    x0 += ks[(g + 1) % 3];
    x1 += ks[(g + 2) % 3] + (unsigned)(g + 1);
  }
}

// ---------------- mega-prologue: sample(2) | transpose(2048) | castT1(3136)
//                  | castT0(256) | pad(512)  — blockIdx-range dispatch
#define PRE_SAMPLE   2
#define PRE_TRANS    (PRE_SAMPLE + 2048)
#define PRE_CAST1    (PRE_TRANS + 3136)
#define PRE_CAST0    (PRE_CAST1 + 256)
#define PRE_TOTAL    (PRE_CAST0 + 512)

__global__ __launch_bounds__(256) void k_pre(const float* __restrict__ proposals,
                                             const float* __restrict__ gt_boxes,
                                             const int* __restrict__ gt_labels,
                                             const float* __restrict__ features,
                                             const float* __restrict__ w1,
                                             const float* __restrict__ w2,
                                             float* __restrict__ prio,
                                             int* __restrict__ plab,
                                             int* __restrict__ matches,
                                             __hip_bfloat16* __restrict__ featT,
                                             __hip_bfloat16* __restrict__ W1T,
                                             __hip_bfloat16* __restrict__ W2T,
                                             __hip_bfloat16* __restrict__ Xb) {
  __shared__ __align__(16) char smem[20800];
  int bid = blockIdx.x;
  int tid = threadIdx.x;
  if (bid < PRE_SAMPLE) {
    // ---------------- sample: rand + IoU match + positive-rank priorities
    float* rs    = (float*)smem;              // 2016
    float* pos_r = (float*)(smem + 8064);     // 2016
    short* pos_i = (short*)(smem + 16128);    // 2016
    float* gtb   = (float*)(smem + 20160);    // 64
    int*   gtl   = (int*)(smem + 20416);      // 16
    int*   cnt   = (int*)(smem + 20480);
    int b = bid;
    int base = b * NPROPS;
    if (tid == 0) *cnt = 0;
    if (tid < N_GT * 4) gtb[tid] = gt_boxes[b * N_GT * 4 + tid];
    if (tid < N_GT) gtl[tid] = gt_labels[b * N_GT + tid];
    __syncthreads();
    for (int i = tid; i < NPROPS; i += 256) {
      unsigned x0 = 0u, x1 = (unsigned)(base + i);
      threefry2x32(0u, 42u, x0, x1);
      unsigned bits = x0 ^ x1;
      float r = __uint_as_float((bits >> 9) | 0x3F800000u) - 1.0f;
      rs[i] = r;
      float p0, p1, p2, p3;
      if (i < N_PROP) {
        const float4 v = *(const float4*)(proposals + ((size_t)b * N_PROP + i) * 4);
        p0 = v.x; p1 = v.y; p2 = v.z; p3 = v.w;
      } else {
        const float* g = &gtb[(i - N_PROP) * 4];
        p0 = g[0]; p1 = g[1]; p2 = g[2]; p3 = g[3];
      }
      float a2 = (p2 - p0) * (p3 - p1);
      float best = -1.0f; int bg = 0;
#pragma unroll
      for (int g = 0; g < N_GT; g++) {
        float g0 = gtb[g*4], g1 = gtb[g*4+1], g2 = gtb[g*4+2], g3 = gtb[g*4+3];
        float a1 = (g2 - g0) * (g3 - g1);
        float wx = fmaxf(fminf(g2, p2) - fmaxf(g0, p0), 0.0f);
        float wy = fmaxf(fminf(g3, p3) - fmaxf(g1, p1), 0.0f);
        float inter = wx * wy;
        float iou = inter / (a1 + a2 - inter);
        if (iou > best) { best = iou; bg = g; }
      }
      matches[base + i] = bg;
      int lab = (best < 0.5f) ? 0 : gtl[bg];
      plab[base + i] = lab;
      if (lab > 0) {
        int s = atomicAdd(cnt, 1);
        pos_i[s] = (short)i; pos_r[s] = r;
      }
    }
    __syncthreads();
    int P = *cnt;
    for (int s = tid; s < P; s += 256) {
      int i = pos_i[s]; float ri = pos_r[s];
      int ch = 0;
      for (int j = 0; j < P; j++) {
        float rj = pos_r[j]; int ij = pos_i[j];
        ch += (rj > ri || (rj == ri && ij < i)) ? 1 : 0;
      }
      rs[i] = (ch < NPOSMAX) ? (ri + 2.0f) : -1000000000.0f;
    }
    __syncthreads();
    for (int i = tid; i < NPROPS; i += 256) prio[base + i] = rs[i];
  } else if (bid < PRE_TRANS) {
    // ---------------- NCHW -> NHWC bf16, 64x64 tiles
    float (*tile)[65] = (float(*)[65])smem;
    int t = bid - PRE_SAMPLE;
    int b = t >> 10;
    int rem = t & 1023;
    int c0 = (rem >> 8) * 64;
    int s0 = (rem & 255) * 64;
    const float* src = features + (size_t)b * C_FEAT * HWF;
    __hip_bfloat16* dst = featT + (size_t)b * HWF * C_FEAT;
    int hw4 = (tid & 15) * 4, cr = tid >> 4;
#pragma unroll
    for (int p = 0; p < 4; p++) {
      int c = cr + p * 16;
      float4 v = *(const float4*)(src + (size_t)(c0 + c) * HWF + s0 + hw4);
      tile[hw4 + 0][c] = v.x; tile[hw4 + 1][c] = v.y;
      tile[hw4 + 2][c] = v.z; tile[hw4 + 3][c] = v.w;
    }
    __syncthreads();
    int c4 = (tid & 15) * 4, hr = tid >> 4;
#pragma unroll
    for (int p = 0; p < 4; p++) {
      int hw = hr + p * 16;
      __hip_bfloat16 o[4] = {__float2bfloat16(tile[hw][c4]), __float2bfloat16(tile[hw][c4+1]),
                             __float2bfloat16(tile[hw][c4+2]), __float2bfloat16(tile[hw][c4+3])};
      *(short4v*)(dst + (size_t)(s0 + hw) * C_FEAT + c0 + c4) = *(short4v*)o;
    }
  } else if (bid < PRE_CAST1) {
    // ---------------- w1 cast: fp32 [c*49+p][N] -> bf16 [N][p*256+c]
    // vectorized: float4 reads (1 KB/wave), short4v writes via LDS column reads
    float (*tile)[65] = (float(*)[65])smem;
    int t = bid - PRE_TRANS;
    int p = t >> 6;
    int rem = t & 63;
    int c0 = (rem & 3) * 64;
    int n0 = (rem >> 2) * 64;
    int n4 = (tid & 15) * 4, ig = tid >> 4;   // 16 row-groups
#pragma unroll
    for (int i = ig; i < 64; i += 16) {
      float4 v = *(const float4*)(w1 + (size_t)((c0 + i) * 49 + p) * HID + n0 + n4);
      tile[i][n4] = v.x; tile[i][n4 + 1] = v.y;
      tile[i][n4 + 2] = v.z; tile[i][n4 + 3] = v.w;
    }
    __syncthreads();
    int c4 = (tid & 15) * 4;
#pragma unroll
    for (int i = ig; i < 64; i += 16) {
      __hip_bfloat16 o[4] = {__float2bfloat16(tile[c4][i]), __float2bfloat16(tile[c4 + 1][i]),
                             __float2bfloat16(tile[c4 + 2][i]), __float2bfloat16(tile[c4 + 3][i])};
      *(short4v*)(W1T + (size_t)(n0 + i) * K1P + p * 256 + c0 + c4) = *(short4v*)o;
    }
  } else if (bid < PRE_CAST0) {
    // ---------------- w2 cast: fp32 [K][N] -> bf16 [N][K], vectorized
    float (*tile)[65] = (float(*)[65])smem;
    int t = bid - PRE_CAST1;
    int c0 = (t & 15) * 64;
    int n0 = (t >> 4) * 64;
    int n4 = (tid & 15) * 4, ig = tid >> 4;
#pragma unroll
    for (int i = ig; i < 64; i += 16) {
      float4 v = *(const float4*)(w2 + (size_t)(c0 + i) * HID + n0 + n4);
      tile[i][n4] = v.x; tile[i][n4 + 1] = v.y;
      tile[i][n4 + 2] = v.z; tile[i][n4 + 3] = v.w;
    }
    __syncthreads();
    int c4 = (tid & 15) * 4;
#pragma unroll
    for (int i = ig; i < 64; i += 16) {
      __hip_bfloat16 o[4] = {__float2bfloat16(tile[c4][i]), __float2bfloat16(tile[c4 + 1][i]),
                             __float2bfloat16(tile[c4 + 2][i]), __float2bfloat16(tile[c4 + 3][i])};
      *(short4v*)(W2T + (size_t)(n0 + i) * HID + c0 + c4) = *(short4v*)o;
    }
  } else {
    // ---------------- zero K-pad cols K1..K1P of Xb / W1T
    int t = bid - PRE_CAST0;        // 0..511
    __hip_bfloat16* buf = (t >> 8) ? W1T : Xb;
    int tt = (t & 255) * 256 + tid;
    int row = tt >> 6;
    int col4 = (tt & 63) << 2;
    short4v z = {0, 0, 0, 0};
    *(short4v*)(buf + (size_t)row * K1P + K1 + col4) = z;
  }
}

// ------------------------------------------------- select + gather + encode
__global__ __launch_bounds__(256) void k_select(const float* __restrict__ prio,
    const float* __restrict__ proposals, const float* __restrict__ gt_boxes,
    const int* __restrict__ matches, const int* __restrict__ plab,
    const float* __restrict__ gt_ell,
    float* __restrict__ sel_boxes, int* __restrict__ sel_labels,
    float* __restrict__ targets) {
  int tid = threadIdx.x;
  int wave = tid >> 6, lane = tid & 63;
  int b = blockIdx.y;
  int base = b * NPROPS;
  int i = blockIdx.x * 4 + wave;
  float pi = prio[base + i];
  int rank = 0;
  for (int j = lane; j < NPROPS; j += 64) {
    float pj = prio[base + j];
    rank += (pj > pi || (pj == pi && j < i)) ? 1 : 0;
  }
#pragma unroll
  for (int off = 32; off > 0; off >>= 1) rank += __shfl_down(rank, off);
  if (lane != 0 || rank >= BPI) return;
  int slot = b * BPI + rank;
  float p0, p1, p2, p3;
  if (i < N_PROP) {
    const float* p = proposals + ((size_t)b * N_PROP + i) * 4;
    p0 = p[0]; p1 = p[1]; p2 = p[2]; p3 = p[3];
  } else {
    const float* p = gt_boxes + ((size_t)b * N_GT + (i - N_PROP)) * 4;
    p0 = p[0]; p1 = p[1]; p2 = p[2]; p3 = p[3];
  }
  sel_boxes[slot * 4 + 0] = p0;
  sel_boxes[slot * 4 + 1] = p1;
  sel_boxes[slot * 4 + 2] = p2;
  sel_boxes[slot * 4 + 3] = p3;
  int lb = plab[base + i];
  sel_labels[slot] = lb;
  int m = matches[base + i];
  const float* e = gt_ell + ((size_t)b * N_GT + m) * 5;
  float ea = e[0], eb = e[1], ex = e[2], ey = e[3], eth = e[4];
  float w = fmaxf(p2 - p0, 1.0f), h = fmaxf(p3 - p1, 1.0f);
  float cx = 0.5f * (p0 + p2), cy = 0.5f * (p1 + p3);
  float* t = targets + (size_t)slot * 6;
  t[0] = (ex - cx) / w;
  t[1] = (ey - cy) / h;
  t[2] = logf(fmaxf(2.0f * ea, 0.001f) / w);
  t[3] = logf(fmaxf(2.0f * eb, 0.001f) / h);
  t[4] = sinf(2.0f * eth);
  t[5] = cosf(2.0f * eth);
}

// ---------------------------------------------------------------- roi align (bf16 feat)
__global__ __launch_bounds__(256) void k_roialign(const __hip_bfloat16* __restrict__ featT,
                                                  const float* __restrict__ sel_boxes,
                                                  __hip_bfloat16* __restrict__ X) {
  int n = blockIdx.x;
  int py = blockIdx.y;
  int t = threadIdx.x;
  int lane = t & 63, sub = t >> 6;
  int c = lane << 2;
  int b = n >> 9;
  const float* bx = sel_boxes + (size_t)n * 4;
  float x1 = bx[0] * 0.125f, y1 = bx[1] * 0.125f;
  float x2 = bx[2] * 0.125f, y2 = bx[3] * 0.125f;
  float bw = fmaxf(x2 - x1, 1.0f) / 7.0f;
  float bh = fmaxf(y2 - y1, 1.0f) / 7.0f;
  const __hip_bfloat16* base = featT + (size_t)b * HWF * C_FEAT;
  int y0A[2]; float lyA[2];
#pragma unroll
  for (int sy = 0; sy < 2; sy++) {
    float off = ((float)(py * 2 + sy) + 0.5f) * 0.5f;
    float ys = fminf(fmaxf(y1 + off * bh, 0.0f), 127.0f);
    int y0 = (int)fminf(fmaxf(floorf(ys), 0.0f), 126.0f);
    y0A[sy] = y0; lyA[sy] = ys - (float)y0;
  }
#pragma unroll
  for (int pass = 0; pass < 2; pass++) {
    int px = sub + (pass << 2);
    if (px >= 7) break;
    float acc[4] = {0.0f, 0.0f, 0.0f, 0.0f};
#pragma unroll
    for (int sx = 0; sx < 2; sx++) {
      float off = ((float)(px * 2 + sx) + 0.5f) * 0.5f;
      float xs = fminf(fmaxf(x1 + off * bw, 0.0f), 127.0f);
      int x0 = (int)fminf(fmaxf(floorf(xs), 0.0f), 126.0f);
      float lx = xs - (float)x0;
#pragma unroll
      for (int sy = 0; sy < 2; sy++) {
        int y0 = y0A[sy]; float ly = lyA[sy];
        const __hip_bfloat16* p = base + ((size_t)(y0 * W_FEAT + x0)) * C_FEAT + c;
        short4v s00 = *(const short4v*)p;
        short4v s01 = *(const short4v*)(p + C_FEAT);
        short4v s10 = *(const short4v*)(p + W_FEAT * C_FEAT);
        short4v s11 = *(const short4v*)(p + W_FEAT * C_FEAT + C_FEAT);
        float w00 = (1.0f - ly) * (1.0f - lx), w01 = (1.0f - ly) * lx;
        float w10 = ly * (1.0f - lx), w11 = ly * lx;
#pragma unroll
        for (int q = 0; q < 4; q++) {
          float v00 = __uint_as_float(((unsigned)(unsigned short)s00[q]) << 16);
          float v01 = __uint_as_float(((unsigned)(unsigned short)s01[q]) << 16);
          float v10 = __uint_as_float(((unsigned)(unsigned short)s10[q]) << 16);
          float v11 = __uint_as_float(((unsigned)(unsigned short)s11[q]) << 16);
          acc[q] += v00 * w00 + v01 * w01 + v10 * w10 + v11 * w11;
        }
      }
    }
    __hip_bfloat16 o[4] = {__float2bfloat16(acc[0] * 0.25f), __float2bfloat16(acc[1] * 0.25f),
                           __float2bfloat16(acc[2] * 0.25f), __float2bfloat16(acc[3] * 0.25f)};
    *(short4v*)&X[(size_t)n * K1P + (size_t)(py * 7 + px) * C_FEAT + c] = *(short4v*)o;
  }
}

// ------------------------------------------------------- bf16 MFMA GEMM (split-K)
// Partials stored PACKED bf16: slab(kz,1M elems) + tile + wave*4096 + frag*256 + lane*4+r
__device__ __forceinline__ void gld_lds16(const __hip_bfloat16* g, __hip_bfloat16* l) {
  __builtin_amdgcn_global_load_lds(
      (const __attribute__((address_space(1))) void*)g,
      (__attribute__((address_space(3))) void*)l, 16, 0, 0);
}

template <int MODE>
__global__ __launch_bounds__(MODE == 1 ? 512 : 256)
void k_mfma_gemm(const __hip_bfloat16* __restrict__ A,
                 const __hip_bfloat16* __restrict__ BT,
                 __hip_bfloat16* __restrict__ Pb, int K, int KC) {
  const int AM  = (MODE == 1) ? 256 : 128;
  const int TPB = AM * 2;
  __shared__ __align__(16) __hip_bfloat16 As[AM * 32];
  __shared__ __align__(16) __hip_bfloat16 Bs[128 * 32];
  int lin = blockIdx.x;
  int n0, m0, kz;
  if (MODE == 1) {
    int c = lin & 7, h = lin >> 8, q = (lin >> 3) & 31;
    kz = c + (h << 3);
    n0 = (q & 7) * 128;
    m0 = (q >> 3) * 256;
  } else {
    kz = lin & 7;
    int q = lin >> 3;
    n0 = (q & 7) * 128;
    m0 = (q >> 3) * 128;
  }
  int tid = threadIdx.x;
  int kbeg = kz * KC;
  int srow = tid >> 2;
  int scs  = tid & 3;
  int sg   = scs ^ (srow & 3);
  int scol = sg << 3;
  int wave = tid >> 6, lane = tid & 63;
  const int WMW = AM / 64;
  int wm = (wave % WMW) * 64, wn = (wave / WMW) * 64;
  int lm = lane & 15, quad = lane >> 4;
  int fco = ((quad ^ (lm & 3)) << 3);
  f32x4f acc[4][4] = {};
  for (int k0 = kbeg; k0 < kbeg + KC; k0 += 32) {
    __syncthreads();
#pragma unroll
    for (int r0 = 0; r0 < AM; r0 += TPB / 4)
      gld_lds16(A + (size_t)(m0 + r0 + srow) * K + k0 + scol, &As[(r0 + srow) * 32 + scs * 8]);
#pragma unroll
    for (int r0 = 0; r0 < 128; r0 += TPB / 4)
      gld_lds16(BT + (size_t)(n0 + r0 + srow) * K + k0 + scol, &Bs[(r0 + srow) * 32 + scs * 8]);
    __syncthreads();
    bf16x8f af[4], bf[4];
#pragma unroll
    for (int i = 0; i < 4; i++)
      af[i] = *(const bf16x8f*)&As[(wm + i * 16 + lm) * 32 + fco];
#pragma unroll
    for (int j = 0; j < 4; j++)
      bf[j] = *(const bf16x8f*)&Bs[(wn + j * 16 + lm) * 32 + fco];
#pragma unroll
    for (int i = 0; i < 4; i++)
#pragma unroll
      for (int j = 0; j < 4; j++)
        acc[i][j] = __builtin_amdgcn_mfma_f32_16x16x32_bf16(af[i], bf[j], acc[i][j], 0, 0, 0);
  }
  int tileoff = (MODE == 1) ? (((m0 >> 8) * 8 + (n0 >> 7)) * 32768)
                            : (((m0 >> 7) * 8 + (n0 >> 7)) * 16384);
  __hip_bfloat16* dst = Pb + ((size_t)kz << 20) + tileoff + wave * 4096 + lane * 4;
#pragma unroll
  for (int i = 0; i < 4; i++)
#pragma unroll
    for (int j = 0; j < 4; j++) {
      __hip_bfloat16 o[4] = {__float2bfloat16(acc[i][j][0]), __float2bfloat16(acc[i][j][1]),
                             __float2bfloat16(acc[i][j][2]), __float2bfloat16(acc[i][j][3])};
      *(short4v*)(dst + (i * 4 + j) * 256) = *(short4v*)o;
    }
}

// ---------------- reduce GEMM1 packed partials + bias + relu -> H1b (bf16)
__global__ __launch_bounds__(256) void k_reduce16(const __hip_bfloat16* __restrict__ Pb,
                                                  const float* __restrict__ bias,
                                                  __hip_bfloat16* __restrict__ O) {
  int m4 = blockIdx.x >> 2;
  int n  = (blockIdx.x & 3) * 256 + threadIdx.x;
  int m0i = m4 >> 6, wavem = (m4 >> 4) & 3, i = (m4 >> 2) & 3, quad = m4 & 3;
  int n0i = n >> 7, wn = (n >> 6) & 1, j = (n >> 4) & 3, lm = n & 15;
  int wave = wavem + wn * 4;
  int elem = (m0i * 8 + n0i) * 32768 + wave * 4096 + (i * 4 + j) * 256 + (quad * 16 + lm) * 4;
  float s0 = 0.0f, s1 = 0.0f, s2 = 0.0f, s3 = 0.0f;
#pragma unroll
  for (int z = 0; z < SPLITK1; z++) {
    short4v v = *(const short4v*)(Pb + ((size_t)z << 20) + elem);
    s0 += __uint_as_float(((unsigned)(unsigned short)v[0]) << 16);
    s1 += __uint_as_float(((unsigned)(unsigned short)v[1]) << 16);
    s2 += __uint_as_float(((unsigned)(unsigned short)v[2]) << 16);
    s3 += __uint_as_float(((unsigned)(unsigned short)v[3]) << 16);
  }
  float bv = bias[n];
  int m = m4 * 4;
  O[(size_t)(m + 0) * HID + n] = __float2bfloat16(fmaxf(s0 + bv, 0.0f));
  O[(size_t)(m + 1) * HID + n] = __float2bfloat16(fmaxf(s1 + bv, 0.0f));
  O[(size_t)(m + 2) * HID + n] = __float2bfloat16(fmaxf(s2 + bv, 0.0f));
  O[(size_t)(m + 3) * HID + n] = __float2bfloat16(fmaxf(s3 + bv, 0.0f));
}

// ---------------- reduce GEMM2 packed partials + bias + relu + head, fused.
__global__ __launch_bounds__(256) void k_reduce_head(const __hip_bfloat16* __restrict__ Pb,
                                                     const float* __restrict__ bias,
                                                     const float* __restrict__ wc,
                                                     const float* __restrict__ bc,
                                                     const float* __restrict__ wr,
                                                     const float* __restrict__ br,
                                                     float* __restrict__ Y) {
  __shared__ float part[4][NHEAD];
  int m = blockIdx.x, tid = threadIdx.x;
  int m0i = m >> 7, wavem = (m >> 6) & 1, fi = (m >> 4) & 3, quad = (m >> 2) & 3, r = m & 3;
  float a[NHEAD];
#pragma unroll
  for (int j = 0; j < NHEAD; j++) a[j] = 0.0f;
#pragma unroll
  for (int nn = 0; nn < 4; nn++) {
    int n = nn * 256 + tid;
    int n0i = n >> 7, wn = (n >> 6) & 1, fj = (n >> 4) & 3, lm = n & 15;
    int wave = wavem + wn * 2;
    int elem = (m0i * 8 + n0i) * 16384 + wave * 4096 + (fi * 4 + fj) * 256
             + (quad * 16 + lm) * 4 + r;
    float s = 0.0f;
#pragma unroll
    for (int z = 0; z < SPLITK2; z++)
      s += __uint_as_float(((unsigned)*(const unsigned short*)(Pb + ((size_t)z << 20) + elem)) << 16);
    float hv = fmaxf(s + bias[n], 0.0f);
    float2 wcv = *(const float2*)(wc + n * 2);
    float4 w0 = *(const float4*)(wr + n * 12);
    float4 w1 = *(const float4*)(wr + n * 12 + 4);
    float4 w2 = *(const float4*)(wr + n * 12 + 8);
    a[0] += hv * wcv.x;  a[1] += hv * wcv.y;
    a[2] += hv * w0.x;   a[3] += hv * w0.y;  a[4] += hv * w0.z;  a[5] += hv * w0.w;
    a[6] += hv * w1.x;   a[7] += hv * w1.y;  a[8] += hv * w1.z;  a[9] += hv * w1.w;
    a[10] += hv * w2.x;  a[11] += hv * w2.y; a[12] += hv * w2.z; a[13] += hv * w2.w;
  }
#pragma unroll
  for (int j = 0; j < NHEAD; j++)
#pragma unroll
    for (int off = 32; off > 0; off >>= 1) a[j] += __shfl_down(a[j], off);
  int wave = tid >> 6, lane = tid & 63;
  if (lane == 0)
#pragma unroll
    for (int j = 0; j < NHEAD; j++) part[wave][j] = a[j];
  __syncthreads();
  if (tid < NHEAD) {
    float v = part[0][tid] + part[1][tid] + part[2][tid] + part[3][tid];
    Y[(size_t)m * NHEAD + tid] = v + ((tid < 2) ? bc[tid] : br[tid - 2]);
  }
}

// ------------------------------------------------------------------- losses
__global__ __launch_bounds__(1024) void k_loss(const float* __restrict__ Y,
                                               const int* __restrict__ sel_labels,
                                               const float* __restrict__ T,
                                               float* __restrict__ out) {
  __shared__ float sc[1024];
  __shared__ float sr[1024];
  int n = threadIdx.x;
  float l0 = Y[(size_t)n * NHEAD + 0], l1 = Y[(size_t)n * NHEAD + 1];
  int lb = sel_labels[n];
  float mx = fmaxf(l0, l1);
  float lse = mx + logf(expf(l0 - mx) + expf(l1 - mx));
  float ce = lse - (lb ? l1 : l0);
  float reg = 0.0f;
  if (lb > 0) {
    const float beta = 1.0f / 9.0f;
    const float* pr = Y + (size_t)n * NHEAD + 2 + lb * 6;
    const float* t = T + (size_t)n * 6;
#pragma unroll
    for (int j = 0; j < 6; j++) {
      float d = fabsf(pr[j] - t[j]);
      reg += (d < beta) ? (0.5f * d * d / beta) : (d - 0.5f * beta);
    }
  }
  sc[n] = ce; sr[n] = reg;
  __syncthreads();
  for (int s = 512; s > 0; s >>= 1) {
    if (n < s) { sc[n] += sc[n + s]; sr[n] += sr[n + s]; }
    __syncthreads();
  }
  if (n == 0) {
    out[0] = sc[0] * (1.0f / 1024.0f);
    out[1] = sr[0] * (1.0f / 1024.0f);
  }
}

// ------------------------------------------------------------------ launch
extern "C" void kernel_launch(void* const* d_in, const int* in_sizes, int n_in,
                              void* d_out, int out_size, void* d_ws, size_t ws_size,
                              hipStream_t stream) {
  const float* features  = (const float*)d_in[0];
  const float* proposals = (const float*)d_in[1];
  const float* gt_boxes  = (const float*)d_in[2];
  const int*   gt_labels = (const int*)d_in[3];
  const float* gt_ell    = (const float*)d_in[4];
  const float* w1 = (const float*)d_in[5];
  const float* b1 = (const float*)d_in[6];
  const float* w2 = (const float*)d_in[7];
  const float* b2 = (const float*)d_in[8];
  const float* wc = (const float*)d_in[9];
  const float* bc = (const float*)d_in[10];
  const float* wr = (const float*)d_in[11];
  const float* br = (const float*)d_in[12];
  float* out = (float*)d_out;

  char* ws = (char*)d_ws;
  size_t off = 0;
  auto take = [&](size_t bytes) -> void* {
    void* p = ws + off;
    off = (off + bytes + 255) & ~(size_t)255;
    return p;
  };
  // Pb (packed bf16 partials, 16 x 2 MiB) hosts featT (16.7 MB) pre-GEMM
  __hip_bfloat16* Pb = (__hip_bfloat16*)take((size_t)SPLITK1 * (1 << 20) * 2); // 33.5 MB
  __hip_bfloat16* featT = Pb;                                                  // alias
  __hip_bfloat16* Xb  = (__hip_bfloat16*)take((size_t)NSEL * K1P * 2);         // 26.2 MB
  float* Y = (float*)Xb;                                                       // alias (post-GEMM1)
  __hip_bfloat16* W1T = (__hip_bfloat16*)take((size_t)HID * K1P * 2);          // 26.2 MB
  __hip_bfloat16* W2T = (__hip_bfloat16*)take((size_t)HID * HID * 2);          // 2.1 MB
  __hip_bfloat16* H1b = (__hip_bfloat16*)take((size_t)NSEL * HID * 2);         // 2.1 MB
  int*   matches   = (int*)take((size_t)B_IMG * NPROPS * 4);
  int*   plab      = (int*)take((size_t)B_IMG * NPROPS * 4);
  float* prio      = (float*)take((size_t)B_IMG * NPROPS * 4);
  float* sel_boxes = (float*)take((size_t)NSEL * 4 * 4);
  int*   sel_lab   = (int*)take((size_t)NSEL * 4);
  float* targets   = (float*)take((size_t)NSEL * 6 * 4);

  k_pre<<<PRE_TOTAL, 256, 0, stream>>>(proposals, gt_boxes, gt_labels, features,
                                       w1, w2, prio, plab, matches,
                                       featT, W1T, W2T, Xb);
  k_select<<<dim3(NPROPS / 4, B_IMG), 256, 0, stream>>>(prio, proposals, gt_boxes,
                                                        matches, plab, gt_ell,
                                                        sel_boxes, sel_lab, targets);
  k_roialign<<<dim3(NSEL, POOL), 256, 0, stream>>>(featT, sel_boxes, Xb);

  // GEMM1: 256x128 tile, split-K=16 (KC=800), 512 blocks, packed bf16 partials
  k_mfma_gemm<1><<<512, 512, 0, stream>>>(Xb, W1T, Pb, K1P, K1P / SPLITK1);
  k_reduce16<<<1024, 256, 0, stream>>>(Pb, b1, H1b);
  // GEMM2: 128x128 tile, split-K=8 (KC=128), 512 blocks -> fused reduce+relu+head
  k_mfma_gemm<2><<<512, 256, 0, stream>>>(H1b, W2T, Pb, HID, HID / SPLITK2);
  k_reduce_head<<<1024, 256, 0, stream>>>(Pb, b2, wc, bc, wr, br, Y);

  k_loss<<<1, 1024, 0, stream>>>(Y, sel_lab, targets, out);
}